// Round 9
// baseline (934.315 us; speedup 1.0000x reference)
//
#include <hip/hip_runtime.h>
#include <hip/hip_bf16.h>
#include <math.h>

// ---------------------------------------------------------------------------
// MLA forward. GEMMs: 256x256 8-phase MFMA schedule (T2 swizzle + counted
// vmcnt + setprio), 16x16x32 MFMA. r9: removed per-phase explicit
// lgkmcnt(0)+sched_barrier(0) — fragment ds_reads are compiler-tracked IR
// loads, so the compiler emits fine-grained lgkmcnt before each dependent
// MFMA (m97 evidence); the full drain serialized LDS against MFMA.
// RoPE via precomputed cos/sin table. G1+G3 fused. rope_kpe+rmsnorm fused.
// Attention QK^T on MFMA (same 16x16x32 fragment mapping as the GEMM).
// ---------------------------------------------------------------------------

typedef __attribute__((ext_vector_type(8))) short short8;
typedef __attribute__((ext_vector_type(4))) short short4x;
typedef __attribute__((ext_vector_type(4))) float floatx4;

__device__ inline float bfbits2f(unsigned short u) {
  union { unsigned int i; float f; } c;
  c.i = ((unsigned int)u) << 16;
  return c.f;
}

#define FENCE() asm volatile("" ::: "memory")
#define BAR()                       \
  do {                              \
    FENCE();                        \
    __builtin_amdgcn_s_barrier();   \
    FENCE();                        \
  } while (0)
#define VMC(n) asm volatile("s_waitcnt vmcnt(" #n ")" ::: "memory")

// -------------------- 256x256 8-phase bf16 GEMM, B transposed --------------
// (structure identical to round-2/round-8 verified kernel, minus LGKM0)
#define RD_A(cb, qm)                                                     \
  {                                                                      \
    _Pragma("unroll") for (int f_ = 0; f_ < 4; f_++) {                   \
      _Pragma("unroll") for (int ks_ = 0; ks_ < 2; ks_++) {              \
        Ar[f_][ks_] = *(const short8*)(ldsb + (cb) * 65536 +             \
            (wm * 128 + (qm) * 64 + f_ * 16 + r15) * 128 +               \
            (((ks_ * 4 + l4) ^ lx) << 4));                               \
      }                                                                  \
    }                                                                    \
  }

#define RD_B(cb, qn, Brg)                                                \
  {                                                                      \
    _Pragma("unroll") for (int g_ = 0; g_ < 2; g_++) {                   \
      _Pragma("unroll") for (int ks_ = 0; ks_ < 2; ks_++) {              \
        Brg[g_][ks_] = *(const short8*)(ldsb + (cb) * 65536 + 32768 +    \
            (wn * 64 + (qn) * 32 + g_ * 16 + r15) * 128 +                \
            (((ks_ * 4 + l4) ^ lx) << 4));                               \
      }                                                                  \
    }                                                                    \
  }

#define MM(qm, qn, B)                                                    \
  {                                                                      \
    _Pragma("unroll") for (int f_ = 0; f_ < 4; f_++) {                   \
      _Pragma("unroll") for (int g_ = 0; g_ < 2; g_++) {                 \
        acc[(qm) * 4 + f_][(qn) * 2 + g_] =                              \
            __builtin_amdgcn_mfma_f32_16x16x32_bf16(                     \
                Ar[f_][0], B[g_][0], acc[(qm) * 4 + f_][(qn) * 2 + g_],  \
                0, 0, 0);                                                \
        acc[(qm) * 4 + f_][(qn) * 2 + g_] =                              \
            __builtin_amdgcn_mfma_f32_16x16x32_bf16(                     \
                Ar[f_][1], B[g_][1], acc[(qm) * 4 + f_][(qn) * 2 + g_],  \
                0, 0, 0);                                                \
      }                                                                  \
    }                                                                    \
  }

template <bool OUT_BF16>
__global__ __launch_bounds__(512, 2) void gemm256_8ph(
    const __hip_bfloat16* __restrict__ A, const __hip_bfloat16* __restrict__ Bt,
    void* __restrict__ C, int Nsplit, int ldc,
    void* __restrict__ C2, int ldc2, int N2,
    int K, int lda, int nbx) {
  __shared__ __hip_bfloat16 lds[2][2][16384];  // [buf][A|B][256*64]
  const int tid = threadIdx.x;
  const int lane = tid & 63;
  const int wave = tid >> 6;
  const int wm = wave >> 2;  // 0..1
  const int wn = wave & 3;   // 0..3
  const int r15 = lane & 15;
  const int l4 = lane >> 4;
  const int lx = lane & 7;

  // XCD-chunked block swizzle (bijective when gridDim %8 == 0).
  const int nwg = gridDim.x;
  int wg = blockIdx.x;
  if ((nwg & 7) == 0) wg = (wg & 7) * (nwg >> 3) + (wg >> 3);
  const int by = wg / nbx;
  const int bx = wg - by * nbx;
  const int m0 = by * 256;
  const int n0 = bx * 256;

  const int lr0 = tid >> 3;
  const int sg0 = (tid & 7) ^ (lr0 & 7);
  const __hip_bfloat16* aSrc = A + (size_t)(m0 + lr0) * lda + sg0 * 8;
  const __hip_bfloat16* bSrc = Bt + (size_t)(n0 + lr0) * (size_t)K + sg0 * 8;

  auto stageA = [&](int cb, int h, int kt) {
#pragma unroll
    for (int i = 0; i < 2; i++) {
      const __hip_bfloat16* src = aSrc + (size_t)((h * 128 + i * 64) * lda + kt);
      __builtin_amdgcn_global_load_lds(
          (const __attribute__((address_space(1))) void*)src,
          (__attribute__((address_space(3))) void*)&lds[cb][0]
              [h * 8192 + (i * 512 + tid) * 8],
          16, 0, 0);
    }
  };
  auto stageB = [&](int cb, int h, int kt) {
#pragma unroll
    for (int i = 0; i < 2; i++) {
      const __hip_bfloat16* src = bSrc + (size_t)((h * 128 + i * 64) * K + kt);
      __builtin_amdgcn_global_load_lds(
          (const __attribute__((address_space(1))) void*)src,
          (__attribute__((address_space(3))) void*)&lds[cb][1]
              [h * 8192 + (i * 512 + tid) * 8],
          16, 0, 0);
    }
  };

  floatx4 acc[8][4] = {};
  short8 Ar[4][2], Br0[2][2], Br1[2][2];
  const char* ldsb = (const char*)&lds[0][0][0];

  // Prologue: buf0 = tile0 (B then A), buf1.B = tile1. 12 loads/thread.
  stageB(0, 0, 0); stageB(0, 1, 0);
  stageA(0, 0, 0); stageA(0, 1, 0);
  stageB(1, 0, 64); stageB(1, 1, 64);
  VMC(4);
  BAR();

  const int niter = K >> 7;
#pragma unroll 1
  for (int it = 0; it < niter; ++it) {
    const int ktc = it * 128;
    const int kt1 = ktc + 64;
    const int t0n = (ktc + 128 < K) ? ktc + 128 : 0;
    const int t1n = (ktc + 192 < K) ? ktc + 192 : 0;

    RD_A(0, 0); RD_B(0, 0, Br0);
    stageA(1, 0, kt1);
    BAR();
    __builtin_amdgcn_s_setprio(1); MM(0, 0, Br0); __builtin_amdgcn_s_setprio(0);
    BAR();
    RD_B(0, 1, Br1);
    stageA(1, 1, kt1);
    BAR();
    __builtin_amdgcn_s_setprio(1); MM(0, 1, Br1); __builtin_amdgcn_s_setprio(0);
    BAR();
    RD_A(0, 1);
    stageB(0, 0, t0n);
    BAR();
    __builtin_amdgcn_s_setprio(1); MM(1, 1, Br1); __builtin_amdgcn_s_setprio(0);
    BAR();
    stageB(0, 1, t0n);
    BAR();
    __builtin_amdgcn_s_setprio(1); MM(1, 0, Br0); __builtin_amdgcn_s_setprio(0);
    VMC(4);
    BAR();
    RD_A(1, 0); RD_B(1, 0, Br0);
    stageA(0, 0, t0n);
    BAR();
    __builtin_amdgcn_s_setprio(1); MM(0, 0, Br0); __builtin_amdgcn_s_setprio(0);
    BAR();
    RD_B(1, 1, Br1);
    stageA(0, 1, t0n);
    BAR();
    __builtin_amdgcn_s_setprio(1); MM(0, 1, Br1); __builtin_amdgcn_s_setprio(0);
    BAR();
    RD_A(1, 1);
    stageB(1, 0, t1n);
    BAR();
    __builtin_amdgcn_s_setprio(1); MM(1, 1, Br1); __builtin_amdgcn_s_setprio(0);
    BAR();
    stageB(1, 1, t1n);
    BAR();
    __builtin_amdgcn_s_setprio(1); MM(1, 0, Br0); __builtin_amdgcn_s_setprio(0);
    VMC(4);
    BAR();
  }
  VMC(0);

  const int crow = l4 * 4;
#pragma unroll
  for (int f = 0; f < 8; f++) {
#pragma unroll
    for (int g = 0; g < 4; g++) {
      const int col = n0 + wn * 64 + g * 16 + r15;
      if (col < Nsplit) {
#pragma unroll
        for (int r = 0; r < 4; r++) {
          const size_t row = (size_t)(m0 + wm * 128 + f * 16 + crow + r);
          if (OUT_BF16)
            ((__hip_bfloat16*)C)[row * ldc + col] =
                __float2bfloat16(acc[f][g][r]);
          else
            ((float*)C)[row * ldc + col] = acc[f][g][r];
        }
      } else if (col - Nsplit < N2) {
        const int c2 = col - Nsplit;
#pragma unroll
        for (int r = 0; r < 4; r++) {
          const size_t row = (size_t)(m0 + wm * 128 + f * 16 + crow + r);
          if (OUT_BF16)
            ((__hip_bfloat16*)C2)[row * ldc2 + c2] =
                __float2bfloat16(acc[f][g][r]);
          else
            ((float*)C2)[row * ldc2 + c2] = acc[f][g][r];
        }
      }
    }
  }
}

// -------------------- weight transpose + cast ------------------------------
__global__ __launch_bounds__(256) void transpose_cast(
    const float* __restrict__ in, __hip_bfloat16* __restrict__ out, int K,
    int N) {
  __shared__ float tile[32][33];
  const int n0 = blockIdx.x * 32, k0 = blockIdx.y * 32;
  const int tx = threadIdx.x & 31, ty = threadIdx.x >> 5;
#pragma unroll
  for (int r = 0; r < 32; r += 8) {
    const int k = k0 + ty + r, n = n0 + tx;
    tile[ty + r][tx] = (n < N) ? in[(size_t)k * N + n] : 0.f;
  }
  __syncthreads();
#pragma unroll
  for (int r = 0; r < 32; r += 8) {
    const int n = n0 + ty + r, k = k0 + tx;
    out[(size_t)n * K + k] = __float2bfloat16(tile[tx][ty + r]);
  }
}

// -------------------- x cast (8 elems/thread, packed short8 store) ---------
__global__ __launch_bounds__(256) void cast_f32_bf16(
    const float* __restrict__ in, __hip_bfloat16* __restrict__ out) {
  const size_t i = ((size_t)blockIdx.x * 256 + threadIdx.x) * 8;
  const float4 v0 = *(const float4*)(in + i);
  const float4 v1 = *(const float4*)(in + i + 4);
  const float f[8] = {v0.x, v0.y, v0.z, v0.w, v1.x, v1.y, v1.z, v1.w};
  short8 o;
#pragma unroll
  for (int k = 0; k < 8; k++) {
    const __hip_bfloat16 b = __float2bfloat16(f[k]);
    o[k] = *(const short*)&b;
  }
  *(short8*)(out + i) = o;
}

// -------------------- RMSNorm (bf16 in-place, short8 vectorized) -----------
__global__ __launch_bounds__(256) void rmsnorm_bf16(
    __hip_bfloat16* __restrict__ x, const float* __restrict__ w, int ncols,
    int stride) {
  __hip_bfloat16* xr = x + (size_t)blockIdx.x * stride;
  float ss = 0.f;
  for (int c = threadIdx.x * 8; c < ncols; c += 2048) {
    const short8 v = *(const short8*)(xr + c);
#pragma unroll
    for (int k = 0; k < 8; k++) {
      const float f = bfbits2f((unsigned short)v[k]);
      ss += f * f;
    }
  }
#pragma unroll
  for (int off = 32; off > 0; off >>= 1) ss += __shfl_down(ss, off);
  __shared__ float wsum[4];
  __shared__ float scale_sh;
  const int wv = threadIdx.x >> 6, lane = threadIdx.x & 63;
  if (lane == 0) wsum[wv] = ss;
  __syncthreads();
  if (threadIdx.x == 0) {
    const float tot = wsum[0] + wsum[1] + wsum[2] + wsum[3];
    scale_sh = rsqrtf(tot / (float)ncols + 1e-6f);
  }
  __syncthreads();
  const float scale = scale_sh;
  for (int c = threadIdx.x * 8; c < ncols; c += 2048) {
    const short8 v = *(const short8*)(xr + c);
    short8 o;
#pragma unroll
    for (int k = 0; k < 8; k++) {
      float f = bfbits2f((unsigned short)v[k]) * scale;
      if (w) f *= w[c + k];
      const __hip_bfloat16 b = __float2bfloat16(f);
      o[k] = *(const short*)&b;
    }
    *(short8*)(xr + c) = o;
  }
}

// -------------------- RoPE cos/sin table (double math, once per (pos,i)) ---
__global__ __launch_bounds__(256) void build_rope_tab(
    float2* __restrict__ tab, const int* __restrict__ start_pos_p) {
  const int idx = blockIdx.x * 256 + threadIdx.x;  // 4096*32
  const int i = idx & 31;
  const int p = idx >> 5;
  const int pos = p + start_pos_p[0];
  const double theta = pow(10000.0, -(double)i / 32.0);
  const double ang = (double)pos * theta;
  tab[idx] = make_float2((float)cos(ang), (float)sin(ang));
}

// -------------------- RoPE on q (bug-compatible positions, table) ----------
__global__ __launch_bounds__(256) void rope_q_bf16(
    __hip_bfloat16* __restrict__ q, const float2* __restrict__ tab, int t0) {
  const int idx = blockIdx.x * 256 + threadIdx.x;  // Tc*16*32
  const int i = idx & 31;
  const int th = idx >> 5;
  const int t = th >> 4;
  const int h = th & 15;
  const int s_idx = (t0 + t) & 4095;
  const int p = (s_idx * 16 + h) & 4095;
  const float2 cs = tab[p * 32 + i];
  const float c = cs.x, s = cs.y;
  __hip_bfloat16* base = q + (size_t)t * 3072 + h * 192 + 128;
  const float x1 = __bfloat162float(base[i]);
  const float x2 = __bfloat162float(base[i + 32]);
  base[i] = __float2bfloat16(x1 * c - x2 * s);
  base[i + 32] = __float2bfloat16(x2 * c + x1 * s);
}

// -------------------- fused RoPE(k_pe) + RMSNorm(kv_c) ---------------------
__global__ __launch_bounds__(128) void rope_rms_kv(
    __hip_bfloat16* __restrict__ kv, const float2* __restrict__ tab) {
  __hip_bfloat16* xr = kv + (size_t)blockIdx.x * 576;
  const int tid = threadIdx.x;
  __shared__ float scale_sh;
  float ss = 0.f;
  short8 v;
  if (tid < 64) {
    v = *(const short8*)(xr + tid * 8);
#pragma unroll
    for (int k = 0; k < 8; k++) {
      const float f = bfbits2f((unsigned short)v[k]);
      ss += f * f;
    }
  } else if (tid < 96) {
    const int i = tid - 64;
    const float2 cs = tab[i];
    __hip_bfloat16* base = xr + 512;
    const float x1 = __bfloat162float(base[i]);
    const float x2 = __bfloat162float(base[i + 32]);
    base[i] = __float2bfloat16(x1 * cs.x - x2 * cs.y);
    base[i + 32] = __float2bfloat16(x2 * cs.x + x1 * cs.y);
  }
#pragma unroll
  for (int off = 32; off > 0; off >>= 1) ss += __shfl_down(ss, off);
  if (tid == 0) scale_sh = rsqrtf(ss / 512.f + 1e-6f);
  __syncthreads();
  if (tid < 64) {
    const float scale = scale_sh;
    short8 o;
#pragma unroll
    for (int k = 0; k < 8; k++) {
      const __hip_bfloat16 b =
          __float2bfloat16(bfbits2f((unsigned short)v[k]) * scale);
      o[k] = *(const short*)&b;
    }
    *(short8*)(xr + tid * 8) = o;
  }
}

// -------------------- wave-per-token attention (MFMA QK^T) -----------------
__global__ __launch_bounds__(256) void attn_wave_token(
    const __hip_bfloat16* __restrict__ q,     // [T][16][192]
    const __hip_bfloat16* __restrict__ kvup,  // [T][16][256] (k_nope|v)
    const __hip_bfloat16* __restrict__ kv,    // [T][576], k_pe at +512
    __hip_bfloat16* __restrict__ ctx) {       // [T][16][128]
  __shared__ __hip_bfloat16 sq[4][16 * 200];
  __shared__ __hip_bfloat16 su[4][16 * 264];
  __shared__ __hip_bfloat16 skpe[4][64];
  __shared__ float sp[4][16][20];  // padded: rows 80B (16B-aligned float4)
  const int tid = threadIdx.x;
  const int w = tid >> 6;
  const int lane = tid & 63;
  const int t = blockIdx.x * 4 + w;

  const __hip_bfloat16* qb = q + (size_t)t * 3072;
  const __hip_bfloat16* ub = kvup + (size_t)t * 4096;
#pragma unroll
  for (int i = 0; i < 6; i++) {
    const int u = lane + 64 * i;  // u < 384
    const int row = u / 24;
    *(short8*)(&sq[w][u * 8 + row * 8]) = *(const short8*)(qb + u * 8);
  }
#pragma unroll
  for (int i = 0; i < 8; i++) {
    const int u = lane + 64 * i;  // u < 512
    const int row = u >> 5;
    *(short8*)(&su[w][u * 8 + row * 8]) = *(const short8*)(ub + u * 8);
  }
  if (lane < 8)
    *(short8*)(&skpe[w][lane * 8]) =
        *(const short8*)(kv + (size_t)t * 576 + 512 + lane * 8);
  __syncthreads();

  const int r15 = lane & 15;
  const int l4 = lane >> 4;

  // ---- QK^T via MFMA: 4 slices from k_nope + 2 from k_pe (broadcast) ----
  floatx4 sacc = {0.f, 0.f, 0.f, 0.f};
#pragma unroll
  for (int ks = 0; ks < 4; ks++) {
    const short8 aq = *(const short8*)(&sq[w][r15 * 200 + ks * 32 + l4 * 8]);
    const short8 bk = *(const short8*)(&su[w][r15 * 264 + ks * 32 + l4 * 8]);
    sacc = __builtin_amdgcn_mfma_f32_16x16x32_bf16(aq, bk, sacc, 0, 0, 0);
  }
#pragma unroll
  for (int ks = 4; ks < 6; ks++) {
    const short8 aq = *(const short8*)(&sq[w][r15 * 200 + ks * 32 + l4 * 8]);
    const short8 bk = *(const short8*)(&skpe[w][(ks - 4) * 32 + l4 * 8]);
    sacc = __builtin_amdgcn_mfma_f32_16x16x32_bf16(aq, bk, sacc, 0, 0, 0);
  }

  // ---- softmax over kh: lane holds S[4*l4+reg][r15]; reduce over r15 ----
  const float scale = 0.07216878364870323f;  // 1/sqrt(192)
  float sv4[4];
#pragma unroll
  for (int r = 0; r < 4; r++) sv4[r] = sacc[r] * scale;
  float mx[4];
#pragma unroll
  for (int r = 0; r < 4; r++) {
    float m = sv4[r];
    m = fmaxf(m, __shfl_xor(m, 1));
    m = fmaxf(m, __shfl_xor(m, 2));
    m = fmaxf(m, __shfl_xor(m, 4));
    m = fmaxf(m, __shfl_xor(m, 8));
    mx[r] = m;
  }
  float e[4];
#pragma unroll
  for (int r = 0; r < 4; r++) {
    e[r] = expf(sv4[r] - mx[r]);
    float s = e[r];
    s += __shfl_xor(s, 1);
    s += __shfl_xor(s, 2);
    s += __shfl_xor(s, 4);
    s += __shfl_xor(s, 8);
    e[r] *= (1.0f / s);
  }
#pragma unroll
  for (int r = 0; r < 4; r++) sp[w][l4 * 4 + r][r15] = e[r];
  __syncthreads();

  // ---- PV (VALU): ctx[hh][d0..d0+3] = sum_j P[hh][j] * V[j][d0..d0+3] ----
  const int d0 = (lane & 31) * 4;
  float vreg[16][4];
#pragma unroll
  for (int j = 0; j < 16; j++) {
    const short4x v4 = *(const short4x*)(&su[w][j * 264 + 128 + d0]);
#pragma unroll
    for (int k = 0; k < 4; k++) vreg[j][k] = bfbits2f((unsigned short)v4[k]);
  }
  const int hb = (lane >> 5) * 8;
  __hip_bfloat16* cb = ctx + (size_t)t * 2048;
#pragma unroll
  for (int g = 0; g < 8; g++) {
    const int hh = hb + g;
    float o[4] = {0.f, 0.f, 0.f, 0.f};
#pragma unroll
    for (int j4 = 0; j4 < 4; j4++) {
      const float4 p4 = *(const float4*)(&sp[w][hh][j4 * 4]);
      const float pj[4] = {p4.x, p4.y, p4.z, p4.w};
#pragma unroll
      for (int jj = 0; jj < 4; jj++) {
        const int j = j4 * 4 + jj;
#pragma unroll
        for (int k = 0; k < 4; k++) o[k] += pj[jj] * vreg[j][k];
      }
    }
    short4x st;
#pragma unroll
    for (int k = 0; k < 4; k++) {
      const __hip_bfloat16 b = __float2bfloat16(o[k]);
      st[k] = *(const short*)&b;
    }
    *(short4x*)(cb + hh * 128 + d0) = st;
  }
}

// ---------------------------------------------------------------------------
extern "C" void kernel_launch(void* const* d_in, const int* in_sizes, int n_in,
                              void* d_out, int out_size, void* d_ws,
                              size_t ws_size, hipStream_t stream) {
  const float* x = (const float*)d_in[0];          // 16384 x 2048
  const float* wq_a = (const float*)d_in[1];       // 2048 x 1536
  const float* q_norm_w = (const float*)d_in[2];   // 1536
  const float* wq_b = (const float*)d_in[3];       // 1536 x 3072
  const float* wkv_a = (const float*)d_in[4];      // 2048 x 576
  const float* wkv_b = (const float*)d_in[5];      // 512 x 4096
  const float* wo = (const float*)d_in[6];         // 2048 x 2048
  const int* start_pos = (const int*)d_in[7];
  float* out = (float*)d_out;

  const int T = 16384;
  __hip_bfloat16* w0 = (__hip_bfloat16*)d_ws;
  __hip_bfloat16* wqkv_aT = w0;                      // 2304 x 2048
  __hip_bfloat16* wq_aT = wqkv_aT;                   // rows 0..1535
  __hip_bfloat16* wkv_aT = wqkv_aT + 1536 * 2048;    // rows 1536..2303 (pad)
  __hip_bfloat16* wq_bT = wqkv_aT + 2304 * 2048;     // 3072 x 1536
  __hip_bfloat16* wkv_bT = wq_bT + 3072 * 1536;      // 4096 x 512
  __hip_bfloat16* woT = wkv_bT + 4096 * 512;         // 2048 x 2048
  float2* rope_tab = (float2*)(woT + 2048 * 2048);   // 4096 x 32 float2 (1MB)
  __hip_bfloat16* chunk0 = (__hip_bfloat16*)(rope_tab + 4096 * 32);
  const size_t w_bytes = (size_t)((char*)chunk0 - (char*)w0);

  const size_t per_tok = 11840 * sizeof(__hip_bfloat16);
  int Tc = T;
  while (Tc > 256 && w_bytes + (size_t)Tc * per_tok > ws_size) Tc >>= 1;

  __hip_bfloat16* xb = chunk0;                       // Tc x 2048
  __hip_bfloat16* q_buf = xb + (size_t)Tc * 2048;    // Tc x 3072
  __hip_bfloat16* kvup = q_buf + (size_t)Tc * 3072;  // Tc x 4096
  __hip_bfloat16* cbuf = kvup + (size_t)Tc * 4096;   // Tc x 2048
  __hip_bfloat16* kv = cbuf + (size_t)Tc * 2048;     // Tc x 576

  dim3 blk(256);
  dim3 blk512(512);

  transpose_cast<<<dim3(1536 / 32, 2048 / 32), blk, 0, stream>>>(wq_a, wq_aT,
                                                                 2048, 1536);
  transpose_cast<<<dim3(768 / 32, 2048 / 32), blk, 0, stream>>>(wkv_a, wkv_aT,
                                                                2048, 576);
  transpose_cast<<<dim3(3072 / 32, 1536 / 32), blk, 0, stream>>>(wq_b, wq_bT,
                                                                 1536, 3072);
  transpose_cast<<<dim3(4096 / 32, 512 / 32), blk, 0, stream>>>(wkv_b, wkv_bT,
                                                                512, 4096);
  transpose_cast<<<dim3(2048 / 32, 2048 / 32), blk, 0, stream>>>(wo, woT, 2048,
                                                                 2048);
  build_rope_tab<<<(4096 * 32) / 256, blk, 0, stream>>>(rope_tab, start_pos);

  const int nby = Tc / 256;
  for (int t0 = 0; t0 < T; t0 += Tc) {
    cast_f32_bf16<<<(Tc * 2048) / 2048, blk, 0, stream>>>(
        x + (size_t)t0 * 2048, xb);
    // G1+G3 fused: [q_lora | kv] = xb @ [wq_a | wkv_a]^T
    gemm256_8ph<true><<<dim3(9 * nby), blk512, 0, stream>>>(
        xb, wqkv_aT, cbuf, 1536, 1536, kv, 576, 576, 2048, 2048, 9);
    rmsnorm_bf16<<<Tc, blk, 0, stream>>>(cbuf, q_norm_w, 1536, 1536);
    rope_rms_kv<<<Tc, dim3(128), 0, stream>>>(kv, rope_tab);
    // G2: q = q_lora @ wq_b^T
    gemm256_8ph<true><<<dim3(12 * nby), blk512, 0, stream>>>(
        cbuf, wq_bT, q_buf, 3072, 3072, nullptr, 0, 0, 1536, 1536, 12);
    rope_q_bf16<<<(Tc * 16 * 32) / 256, blk, 0, stream>>>(q_buf, rope_tab, t0);
    // G4: kvup = kvn @ wkv_b^T (A ld 576, K=512)
    gemm256_8ph<true><<<dim3(16 * nby), blk512, 0, stream>>>(
        kv, wkv_bT, kvup, 4096, 4096, nullptr, 0, 0, 512, 576, 16);
    // attention -> ctx (reuses cbuf)
    attn_wave_token<<<Tc / 4, blk, 0, stream>>>(q_buf, kvup, kv, cbuf);
    // G5: out = ctx @ wo^T (fp32 out)
    gemm256_8ph<false><<<dim3(8 * nby), blk512, 0, stream>>>(
        cbuf, woT, out + (size_t)t0 * 2048, 2048, 2048, nullptr, 0, 0, 2048,
        2048, 8);
  }
}

// Round 10
// 916.820 us; speedup vs baseline: 1.0191x; 1.0191x over previous
//
#include <hip/hip_runtime.h>
#include <hip/hip_bf16.h>
#include <math.h>

// ---------------------------------------------------------------------------
// MLA forward. GEMMs: 256x256 8-phase MFMA schedule (T2 swizzle + counted
// vmcnt + setprio), 16x16x32 MFMA — round-2/round-8 verified schedule
// (LGKM0 restored: r9 A/B showed its removal is null on GEMM counters).
// RoPE via precomputed cos/sin table. G1+G3 fused. rope_kpe+rmsnorm fused.
// Attention: QK^T on MFMA; V read direct from global (L3) — only k_nope
// staged in LDS -> ~49 KB/block, 3 blocks/CU.
// ---------------------------------------------------------------------------

typedef __attribute__((ext_vector_type(8))) short short8;
typedef __attribute__((ext_vector_type(4))) short short4x;
typedef __attribute__((ext_vector_type(4))) float floatx4;

__device__ inline float bfbits2f(unsigned short u) {
  union { unsigned int i; float f; } c;
  c.i = ((unsigned int)u) << 16;
  return c.f;
}

#define FENCE() asm volatile("" ::: "memory")
#define BAR()                       \
  do {                              \
    FENCE();                        \
    __builtin_amdgcn_s_barrier();   \
    FENCE();                        \
  } while (0)
#define LGKM0()                                       \
  do {                                                \
    asm volatile("s_waitcnt lgkmcnt(0)" ::: "memory");\
    __builtin_amdgcn_sched_barrier(0);                \
  } while (0)
#define VMC(n) asm volatile("s_waitcnt vmcnt(" #n ")" ::: "memory")

// -------------------- 256x256 8-phase bf16 GEMM, B transposed --------------
// (structure identical to round-2/round-8 verified kernel)
#define RD_A(cb, qm)                                                     \
  {                                                                      \
    _Pragma("unroll") for (int f_ = 0; f_ < 4; f_++) {                   \
      _Pragma("unroll") for (int ks_ = 0; ks_ < 2; ks_++) {              \
        Ar[f_][ks_] = *(const short8*)(ldsb + (cb) * 65536 +             \
            (wm * 128 + (qm) * 64 + f_ * 16 + r15) * 128 +               \
            (((ks_ * 4 + l4) ^ lx) << 4));                               \
      }                                                                  \
    }                                                                    \
  }

#define RD_B(cb, qn, Brg)                                                \
  {                                                                      \
    _Pragma("unroll") for (int g_ = 0; g_ < 2; g_++) {                   \
      _Pragma("unroll") for (int ks_ = 0; ks_ < 2; ks_++) {              \
        Brg[g_][ks_] = *(const short8*)(ldsb + (cb) * 65536 + 32768 +    \
            (wn * 64 + (qn) * 32 + g_ * 16 + r15) * 128 +                \
            (((ks_ * 4 + l4) ^ lx) << 4));                               \
      }                                                                  \
    }                                                                    \
  }

#define MM(qm, qn, B)                                                    \
  {                                                                      \
    _Pragma("unroll") for (int f_ = 0; f_ < 4; f_++) {                   \
      _Pragma("unroll") for (int g_ = 0; g_ < 2; g_++) {                 \
        acc[(qm) * 4 + f_][(qn) * 2 + g_] =                              \
            __builtin_amdgcn_mfma_f32_16x16x32_bf16(                     \
                Ar[f_][0], B[g_][0], acc[(qm) * 4 + f_][(qn) * 2 + g_],  \
                0, 0, 0);                                                \
        acc[(qm) * 4 + f_][(qn) * 2 + g_] =                              \
            __builtin_amdgcn_mfma_f32_16x16x32_bf16(                     \
                Ar[f_][1], B[g_][1], acc[(qm) * 4 + f_][(qn) * 2 + g_],  \
                0, 0, 0);                                                \
      }                                                                  \
    }                                                                    \
  }

template <bool OUT_BF16>
__global__ __launch_bounds__(512, 2) void gemm256_8ph(
    const __hip_bfloat16* __restrict__ A, const __hip_bfloat16* __restrict__ Bt,
    void* __restrict__ C, int Nsplit, int ldc,
    void* __restrict__ C2, int ldc2, int N2,
    int K, int lda, int nbx) {
  __shared__ __hip_bfloat16 lds[2][2][16384];  // [buf][A|B][256*64]
  const int tid = threadIdx.x;
  const int lane = tid & 63;
  const int wave = tid >> 6;
  const int wm = wave >> 2;  // 0..1
  const int wn = wave & 3;   // 0..3
  const int r15 = lane & 15;
  const int l4 = lane >> 4;
  const int lx = lane & 7;

  // XCD-chunked block swizzle (bijective when gridDim %8 == 0).
  const int nwg = gridDim.x;
  int wg = blockIdx.x;
  if ((nwg & 7) == 0) wg = (wg & 7) * (nwg >> 3) + (wg >> 3);
  const int by = wg / nbx;
  const int bx = wg - by * nbx;
  const int m0 = by * 256;
  const int n0 = bx * 256;

  const int lr0 = tid >> 3;
  const int sg0 = (tid & 7) ^ (lr0 & 7);
  const __hip_bfloat16* aSrc = A + (size_t)(m0 + lr0) * lda + sg0 * 8;
  const __hip_bfloat16* bSrc = Bt + (size_t)(n0 + lr0) * (size_t)K + sg0 * 8;

  auto stageA = [&](int cb, int h, int kt) {
#pragma unroll
    for (int i = 0; i < 2; i++) {
      const __hip_bfloat16* src = aSrc + (size_t)((h * 128 + i * 64) * lda + kt);
      __builtin_amdgcn_global_load_lds(
          (const __attribute__((address_space(1))) void*)src,
          (__attribute__((address_space(3))) void*)&lds[cb][0]
              [h * 8192 + (i * 512 + tid) * 8],
          16, 0, 0);
    }
  };
  auto stageB = [&](int cb, int h, int kt) {
#pragma unroll
    for (int i = 0; i < 2; i++) {
      const __hip_bfloat16* src = bSrc + (size_t)((h * 128 + i * 64) * K + kt);
      __builtin_amdgcn_global_load_lds(
          (const __attribute__((address_space(1))) void*)src,
          (__attribute__((address_space(3))) void*)&lds[cb][1]
              [h * 8192 + (i * 512 + tid) * 8],
          16, 0, 0);
    }
  };

  floatx4 acc[8][4] = {};
  short8 Ar[4][2], Br0[2][2], Br1[2][2];
  const char* ldsb = (const char*)&lds[0][0][0];

  // Prologue: buf0 = tile0 (B then A), buf1.B = tile1. 12 loads/thread.
  stageB(0, 0, 0); stageB(0, 1, 0);
  stageA(0, 0, 0); stageA(0, 1, 0);
  stageB(1, 0, 64); stageB(1, 1, 64);
  VMC(4);
  BAR();

  const int niter = K >> 7;
#pragma unroll 1
  for (int it = 0; it < niter; ++it) {
    const int ktc = it * 128;
    const int kt1 = ktc + 64;
    const int t0n = (ktc + 128 < K) ? ktc + 128 : 0;
    const int t1n = (ktc + 192 < K) ? ktc + 192 : 0;

    RD_A(0, 0); RD_B(0, 0, Br0);
    stageA(1, 0, kt1);
    BAR(); LGKM0();
    __builtin_amdgcn_s_setprio(1); MM(0, 0, Br0); __builtin_amdgcn_s_setprio(0);
    BAR();
    RD_B(0, 1, Br1);
    stageA(1, 1, kt1);
    BAR(); LGKM0();
    __builtin_amdgcn_s_setprio(1); MM(0, 1, Br1); __builtin_amdgcn_s_setprio(0);
    BAR();
    RD_A(0, 1);
    stageB(0, 0, t0n);
    BAR(); LGKM0();
    __builtin_amdgcn_s_setprio(1); MM(1, 1, Br1); __builtin_amdgcn_s_setprio(0);
    BAR();
    stageB(0, 1, t0n);
    BAR();
    __builtin_amdgcn_s_setprio(1); MM(1, 0, Br0); __builtin_amdgcn_s_setprio(0);
    VMC(4);
    BAR();
    RD_A(1, 0); RD_B(1, 0, Br0);
    stageA(0, 0, t0n);
    BAR(); LGKM0();
    __builtin_amdgcn_s_setprio(1); MM(0, 0, Br0); __builtin_amdgcn_s_setprio(0);
    BAR();
    RD_B(1, 1, Br1);
    stageA(0, 1, t0n);
    BAR(); LGKM0();
    __builtin_amdgcn_s_setprio(1); MM(0, 1, Br1); __builtin_amdgcn_s_setprio(0);
    BAR();
    RD_A(1, 1);
    stageB(1, 0, t1n);
    BAR(); LGKM0();
    __builtin_amdgcn_s_setprio(1); MM(1, 1, Br1); __builtin_amdgcn_s_setprio(0);
    BAR();
    stageB(1, 1, t1n);
    BAR();
    __builtin_amdgcn_s_setprio(1); MM(1, 0, Br0); __builtin_amdgcn_s_setprio(0);
    VMC(4);
    BAR();
  }
  VMC(0);

  const int crow = l4 * 4;
#pragma unroll
  for (int f = 0; f < 8; f++) {
#pragma unroll
    for (int g = 0; g < 4; g++) {
      const int col = n0 + wn * 64 + g * 16 + r15;
      if (col < Nsplit) {
#pragma unroll
        for (int r = 0; r < 4; r++) {
          const size_t row = (size_t)(m0 + wm * 128 + f * 16 + crow + r);
          if (OUT_BF16)
            ((__hip_bfloat16*)C)[row * ldc + col] =
                __float2bfloat16(acc[f][g][r]);
          else
            ((float*)C)[row * ldc + col] = acc[f][g][r];
        }
      } else if (col - Nsplit < N2) {
        const int c2 = col - Nsplit;
#pragma unroll
        for (int r = 0; r < 4; r++) {
          const size_t row = (size_t)(m0 + wm * 128 + f * 16 + crow + r);
          if (OUT_BF16)
            ((__hip_bfloat16*)C2)[row * ldc2 + c2] =
                __float2bfloat16(acc[f][g][r]);
          else
            ((float*)C2)[row * ldc2 + c2] = acc[f][g][r];
        }
      }
    }
  }
}

// -------------------- weight transpose + cast ------------------------------
__global__ __launch_bounds__(256) void transpose_cast(
    const float* __restrict__ in, __hip_bfloat16* __restrict__ out, int K,
    int N) {
  __shared__ float tile[32][33];
  const int n0 = blockIdx.x * 32, k0 = blockIdx.y * 32;
  const int tx = threadIdx.x & 31, ty = threadIdx.x >> 5;
#pragma unroll
  for (int r = 0; r < 32; r += 8) {
    const int k = k0 + ty + r, n = n0 + tx;
    tile[ty + r][tx] = (n < N) ? in[(size_t)k * N + n] : 0.f;
  }
  __syncthreads();
#pragma unroll
  for (int r = 0; r < 32; r += 8) {
    const int n = n0 + ty + r, k = k0 + tx;
    out[(size_t)n * K + k] = __float2bfloat16(tile[tx][ty + r]);
  }
}

// -------------------- x cast (8 elems/thread, packed short8 store) ---------
__global__ __launch_bounds__(256) void cast_f32_bf16(
    const float* __restrict__ in, __hip_bfloat16* __restrict__ out) {
  const size_t i = ((size_t)blockIdx.x * 256 + threadIdx.x) * 8;
  const float4 v0 = *(const float4*)(in + i);
  const float4 v1 = *(const float4*)(in + i + 4);
  const float f[8] = {v0.x, v0.y, v0.z, v0.w, v1.x, v1.y, v1.z, v1.w};
  short8 o;
#pragma unroll
  for (int k = 0; k < 8; k++) {
    const __hip_bfloat16 b = __float2bfloat16(f[k]);
    o[k] = *(const short*)&b;
  }
  *(short8*)(out + i) = o;
}

// -------------------- RMSNorm (bf16 in-place, short8 vectorized) -----------
__global__ __launch_bounds__(256) void rmsnorm_bf16(
    __hip_bfloat16* __restrict__ x, const float* __restrict__ w, int ncols,
    int stride) {
  __hip_bfloat16* xr = x + (size_t)blockIdx.x * stride;
  float ss = 0.f;
  for (int c = threadIdx.x * 8; c < ncols; c += 2048) {
    const short8 v = *(const short8*)(xr + c);
#pragma unroll
    for (int k = 0; k < 8; k++) {
      const float f = bfbits2f((unsigned short)v[k]);
      ss += f * f;
    }
  }
#pragma unroll
  for (int off = 32; off > 0; off >>= 1) ss += __shfl_down(ss, off);
  __shared__ float wsum[4];
  __shared__ float scale_sh;
  const int wv = threadIdx.x >> 6, lane = threadIdx.x & 63;
  if (lane == 0) wsum[wv] = ss;
  __syncthreads();
  if (threadIdx.x == 0) {
    const float tot = wsum[0] + wsum[1] + wsum[2] + wsum[3];
    scale_sh = rsqrtf(tot / (float)ncols + 1e-6f);
  }
  __syncthreads();
  const float scale = scale_sh;
  for (int c = threadIdx.x * 8; c < ncols; c += 2048) {
    const short8 v = *(const short8*)(xr + c);
    short8 o;
#pragma unroll
    for (int k = 0; k < 8; k++) {
      float f = bfbits2f((unsigned short)v[k]) * scale;
      if (w) f *= w[c + k];
      const __hip_bfloat16 b = __float2bfloat16(f);
      o[k] = *(const short*)&b;
    }
    *(short8*)(xr + c) = o;
  }
}

// -------------------- RoPE cos/sin table (double math, once per (pos,i)) ---
__global__ __launch_bounds__(256) void build_rope_tab(
    float2* __restrict__ tab, const int* __restrict__ start_pos_p) {
  const int idx = blockIdx.x * 256 + threadIdx.x;  // 4096*32
  const int i = idx & 31;
  const int p = idx >> 5;
  const int pos = p + start_pos_p[0];
  const double theta = pow(10000.0, -(double)i / 32.0);
  const double ang = (double)pos * theta;
  tab[idx] = make_float2((float)cos(ang), (float)sin(ang));
}

// -------------------- RoPE on q (bug-compatible positions, table) ----------
__global__ __launch_bounds__(256) void rope_q_bf16(
    __hip_bfloat16* __restrict__ q, const float2* __restrict__ tab, int t0) {
  const int idx = blockIdx.x * 256 + threadIdx.x;  // Tc*16*32
  const int i = idx & 31;
  const int th = idx >> 5;
  const int t = th >> 4;
  const int h = th & 15;
  const int s_idx = (t0 + t) & 4095;
  const int p = (s_idx * 16 + h) & 4095;
  const float2 cs = tab[p * 32 + i];
  const float c = cs.x, s = cs.y;
  __hip_bfloat16* base = q + (size_t)t * 3072 + h * 192 + 128;
  const float x1 = __bfloat162float(base[i]);
  const float x2 = __bfloat162float(base[i + 32]);
  base[i] = __float2bfloat16(x1 * c - x2 * s);
  base[i + 32] = __float2bfloat16(x2 * c + x1 * s);
}

// -------------------- fused RoPE(k_pe) + RMSNorm(kv_c) ---------------------
__global__ __launch_bounds__(128) void rope_rms_kv(
    __hip_bfloat16* __restrict__ kv, const float2* __restrict__ tab) {
  __hip_bfloat16* xr = kv + (size_t)blockIdx.x * 576;
  const int tid = threadIdx.x;
  __shared__ float scale_sh;
  float ss = 0.f;
  short8 v;
  if (tid < 64) {
    v = *(const short8*)(xr + tid * 8);
#pragma unroll
    for (int k = 0; k < 8; k++) {
      const float f = bfbits2f((unsigned short)v[k]);
      ss += f * f;
    }
  } else if (tid < 96) {
    const int i = tid - 64;
    const float2 cs = tab[i];
    __hip_bfloat16* base = xr + 512;
    const float x1 = __bfloat162float(base[i]);
    const float x2 = __bfloat162float(base[i + 32]);
    base[i] = __float2bfloat16(x1 * cs.x - x2 * cs.y);
    base[i + 32] = __float2bfloat16(x2 * cs.x + x1 * cs.y);
  }
#pragma unroll
  for (int off = 32; off > 0; off >>= 1) ss += __shfl_down(ss, off);
  if (tid == 0) scale_sh = rsqrtf(ss / 512.f + 1e-6f);
  __syncthreads();
  if (tid < 64) {
    const float scale = scale_sh;
    short8 o;
#pragma unroll
    for (int k = 0; k < 8; k++) {
      const __hip_bfloat16 b =
          __float2bfloat16(bfbits2f((unsigned short)v[k]) * scale);
      o[k] = *(const short*)&b;
    }
    *(short8*)(xr + tid * 8) = o;
  }
}

// -------------------- wave-per-token attention (MFMA QK^T, V direct) -------
// S[qh][kh] via 6x mfma_f32_16x16x32_bf16 (verified fragment mapping).
// Only k_nope staged in LDS (V read once -> direct from global/L3).
__global__ __launch_bounds__(256) void attn_wave_token(
    const __hip_bfloat16* __restrict__ q,     // [T][16][192]
    const __hip_bfloat16* __restrict__ kvup,  // [T][16][256] (k_nope|v)
    const __hip_bfloat16* __restrict__ kv,    // [T][576], k_pe at +512
    __hip_bfloat16* __restrict__ ctx) {       // [T][16][128]
  __shared__ __hip_bfloat16 sq[4][16 * 200];
  __shared__ __hip_bfloat16 su[4][16 * 136];  // k_nope only, +8 pad
  __shared__ __hip_bfloat16 skpe[4][64];
  __shared__ float sp[4][16][20];  // padded: rows 80B (16B-aligned float4)
  const int tid = threadIdx.x;
  const int w = tid >> 6;
  const int lane = tid & 63;
  const int t = blockIdx.x * 4 + w;

  const __hip_bfloat16* qb = q + (size_t)t * 3072;
  const __hip_bfloat16* ub = kvup + (size_t)t * 4096;
#pragma unroll
  for (int i = 0; i < 6; i++) {
    const int u = lane + 64 * i;  // u < 384
    const int row = u / 24;
    *(short8*)(&sq[w][u * 8 + row * 8]) = *(const short8*)(qb + u * 8);
  }
  // k_nope: row j = u>>4, unit (u&15) of 16 per row; global row stride 256.
#pragma unroll
  for (int i = 0; i < 4; i++) {
    const int u = lane + 64 * i;  // u < 256
    const int row = u >> 4;
    *(short8*)(&su[w][u * 8 + row * 8]) =
        *(const short8*)(ub + row * 256 + (u & 15) * 8);
  }
  if (lane < 8)
    *(short8*)(&skpe[w][lane * 8]) =
        *(const short8*)(kv + (size_t)t * 576 + 512 + lane * 8);
  __syncthreads();

  const int r15 = lane & 15;
  const int l4 = lane >> 4;

  // ---- QK^T via MFMA: 4 slices from k_nope + 2 from k_pe (broadcast) ----
  floatx4 sacc = {0.f, 0.f, 0.f, 0.f};
#pragma unroll
  for (int ks = 0; ks < 4; ks++) {
    const short8 aq = *(const short8*)(&sq[w][r15 * 200 + ks * 32 + l4 * 8]);
    const short8 bk = *(const short8*)(&su[w][r15 * 136 + ks * 32 + l4 * 8]);
    sacc = __builtin_amdgcn_mfma_f32_16x16x32_bf16(aq, bk, sacc, 0, 0, 0);
  }
#pragma unroll
  for (int ks = 4; ks < 6; ks++) {
    const short8 aq = *(const short8*)(&sq[w][r15 * 200 + ks * 32 + l4 * 8]);
    const short8 bk = *(const short8*)(&skpe[w][(ks - 4) * 32 + l4 * 8]);
    sacc = __builtin_amdgcn_mfma_f32_16x16x32_bf16(aq, bk, sacc, 0, 0, 0);
  }

  // ---- V loads (global, L3-resident; issued early to hide latency) ----
  const int d0 = (lane & 31) * 4;
  float vreg[16][4];
#pragma unroll
  for (int j = 0; j < 16; j++) {
    const short4x v4 = *(const short4x*)(ub + j * 256 + 128 + d0);
#pragma unroll
    for (int k = 0; k < 4; k++) vreg[j][k] = bfbits2f((unsigned short)v4[k]);
  }

  // ---- softmax over kh: lane holds S[4*l4+reg][r15]; reduce over r15 ----
  const float scale = 0.07216878364870323f;  // 1/sqrt(192)
  float sv4[4];
#pragma unroll
  for (int r = 0; r < 4; r++) sv4[r] = sacc[r] * scale;
  float mx[4];
#pragma unroll
  for (int r = 0; r < 4; r++) {
    float m = sv4[r];
    m = fmaxf(m, __shfl_xor(m, 1));
    m = fmaxf(m, __shfl_xor(m, 2));
    m = fmaxf(m, __shfl_xor(m, 4));
    m = fmaxf(m, __shfl_xor(m, 8));
    mx[r] = m;
  }
  float e[4];
#pragma unroll
  for (int r = 0; r < 4; r++) {
    e[r] = expf(sv4[r] - mx[r]);
    float s = e[r];
    s += __shfl_xor(s, 1);
    s += __shfl_xor(s, 2);
    s += __shfl_xor(s, 4);
    s += __shfl_xor(s, 8);
    e[r] *= (1.0f / s);
  }
#pragma unroll
  for (int r = 0; r < 4; r++) sp[w][l4 * 4 + r][r15] = e[r];
  __syncthreads();

  // ---- PV (VALU): ctx[hh][d0..d0+3] = sum_j P[hh][j] * V[j][d0..d0+3] ----
  const int hb = (lane >> 5) * 8;
  __hip_bfloat16* cb = ctx + (size_t)t * 2048;
#pragma unroll
  for (int g = 0; g < 8; g++) {
    const int hh = hb + g;
    float o[4] = {0.f, 0.f, 0.f, 0.f};
#pragma unroll
    for (int j4 = 0; j4 < 4; j4++) {
      const float4 p4 = *(const float4*)(&sp[w][hh][j4 * 4]);
      const float pj[4] = {p4.x, p4.y, p4.z, p4.w};
#pragma unroll
      for (int jj = 0; jj < 4; jj++) {
        const int j = j4 * 4 + jj;
#pragma unroll
        for (int k = 0; k < 4; k++) o[k] += pj[jj] * vreg[j][k];
      }
    }
    short4x st;
#pragma unroll
    for (int k = 0; k < 4; k++) {
      const __hip_bfloat16 b = __float2bfloat16(o[k]);
      st[k] = *(const short*)&b;
    }
    *(short4x*)(cb + hh * 128 + d0) = st;
  }
}

// ---------------------------------------------------------------------------
extern "C" void kernel_launch(void* const* d_in, const int* in_sizes, int n_in,
                              void* d_out, int out_size, void* d_ws,
                              size_t ws_size, hipStream_t stream) {
  const float* x = (const float*)d_in[0];          // 16384 x 2048
  const float* wq_a = (const float*)d_in[1];       // 2048 x 1536
  const float* q_norm_w = (const float*)d_in[2];   // 1536
  const float* wq_b = (const float*)d_in[3];       // 1536 x 3072
  const float* wkv_a = (const float*)d_in[4];      // 2048 x 576
  const float* wkv_b = (const float*)d_in[5];      // 512 x 4096
  const float* wo = (const float*)d_in[6];         // 2048 x 2048
  const int* start_pos = (const int*)d_in[7];
  float* out = (float*)d_out;

  const int T = 16384;
  __hip_bfloat16* w0 = (__hip_bfloat16*)d_ws;
  __hip_bfloat16* wqkv_aT = w0;                      // 2304 x 2048
  __hip_bfloat16* wq_aT = wqkv_aT;                   // rows 0..1535
  __hip_bfloat16* wkv_aT = wqkv_aT + 1536 * 2048;    // rows 1536..2303 (pad)
  __hip_bfloat16* wq_bT = wqkv_aT + 2304 * 2048;     // 3072 x 1536
  __hip_bfloat16* wkv_bT = wq_bT + 3072 * 1536;      // 4096 x 512
  __hip_bfloat16* woT = wkv_bT + 4096 * 512;         // 2048 x 2048
  float2* rope_tab = (float2*)(woT + 2048 * 2048);   // 4096 x 32 float2 (1MB)
  __hip_bfloat16* chunk0 = (__hip_bfloat16*)(rope_tab + 4096 * 32);
  const size_t w_bytes = (size_t)((char*)chunk0 - (char*)w0);

  const size_t per_tok = 11840 * sizeof(__hip_bfloat16);
  int Tc = T;
  while (Tc > 256 && w_bytes + (size_t)Tc * per_tok > ws_size) Tc >>= 1;

  __hip_bfloat16* xb = chunk0;                       // Tc x 2048
  __hip_bfloat16* q_buf = xb + (size_t)Tc * 2048;    // Tc x 3072
  __hip_bfloat16* kvup = q_buf + (size_t)Tc * 3072;  // Tc x 4096
  __hip_bfloat16* cbuf = kvup + (size_t)Tc * 4096;   // Tc x 2048
  __hip_bfloat16* kv = cbuf + (size_t)Tc * 2048;     // Tc x 576

  dim3 blk(256);
  dim3 blk512(512);

  transpose_cast<<<dim3(1536 / 32, 2048 / 32), blk, 0, stream>>>(wq_a, wq_aT,
                                                                 2048, 1536);
  transpose_cast<<<dim3(768 / 32, 2048 / 32), blk, 0, stream>>>(wkv_a, wkv_aT,
                                                                2048, 576);
  transpose_cast<<<dim3(3072 / 32, 1536 / 32), blk, 0, stream>>>(wq_b, wq_bT,
                                                                 1536, 3072);
  transpose_cast<<<dim3(4096 / 32, 512 / 32), blk, 0, stream>>>(wkv_b, wkv_bT,
                                                                512, 4096);
  transpose_cast<<<dim3(2048 / 32, 2048 / 32), blk, 0, stream>>>(wo, woT, 2048,
                                                                 2048);
  build_rope_tab<<<(4096 * 32) / 256, blk, 0, stream>>>(rope_tab, start_pos);

  const int nby = Tc / 256;
  for (int t0 = 0; t0 < T; t0 += Tc) {
    cast_f32_bf16<<<(Tc * 2048) / 2048, blk, 0, stream>>>(
        x + (size_t)t0 * 2048, xb);
    // G1+G3 fused: [q_lora | kv] = xb @ [wq_a | wkv_a]^T
    gemm256_8ph<true><<<dim3(9 * nby), blk512, 0, stream>>>(
        xb, wqkv_aT, cbuf, 1536, 1536, kv, 576, 576, 2048, 2048, 9);
    rmsnorm_bf16<<<Tc, blk, 0, stream>>>(cbuf, q_norm_w, 1536, 1536);
    rope_rms_kv<<<Tc, dim3(128), 0, stream>>>(kv, rope_tab);
    // G2: q = q_lora @ wq_b^T
    gemm256_8ph<true><<<dim3(12 * nby), blk512, 0, stream>>>(
        cbuf, wq_bT, q_buf, 3072, 3072, nullptr, 0, 0, 1536, 1536, 12);
    rope_q_bf16<<<(Tc * 16 * 32) / 256, blk, 0, stream>>>(q_buf, rope_tab, t0);
    // G4: kvup = kvn @ wkv_b^T (A ld 576, K=512)
    gemm256_8ph<true><<<dim3(16 * nby), blk512, 0, stream>>>(
        kv, wkv_bT, kvup, 4096, 4096, nullptr, 0, 0, 512, 576, 16);
    // attention -> ctx (reuses cbuf)
    attn_wave_token<<<Tc / 4, blk, 0, stream>>>(q_buf, kvup, kv, cbuf);
    // G5: out = ctx @ wo^T (fp32 out)
    gemm256_8ph<false><<<dim3(8 * nby), blk512, 0, stream>>>(
        cbuf, woT, out + (size_t)t0 * 2048, 2048, 2048, nullptr, 0, 0, 2048,
        2048, 8);
  }
}

// Round 11
// 907.584 us; speedup vs baseline: 1.0295x; 1.0102x over previous
//
#include <hip/hip_runtime.h>
#include <hip/hip_bf16.h>
#include <math.h>

// ---------------------------------------------------------------------------
// MLA forward. GEMMs: 256x256 8-phase MFMA schedule (T2 swizzle + counted
// vmcnt + setprio), 16x16x32 MFMA — round-2/round-8 verified schedule.
// RoPE via precomputed cos/sin table. G1+G3 fused. rope_kpe+rmsnorm fused.
// r11: rope_q fused into G2's epilogue (window = one wn group; pair (i,i+32)
// = acc[f][g] <-> acc[f][g+2]; rotation on f32 acc pre-rounding).
// Attention: QK^T on MFMA; V direct from global (L3); k_nope-only LDS.
// ---------------------------------------------------------------------------

typedef __attribute__((ext_vector_type(8))) short short8;
typedef __attribute__((ext_vector_type(4))) short short4x;
typedef __attribute__((ext_vector_type(4))) float floatx4;

__device__ inline float bfbits2f(unsigned short u) {
  union { unsigned int i; float f; } c;
  c.i = ((unsigned int)u) << 16;
  return c.f;
}

#define FENCE() asm volatile("" ::: "memory")
#define BAR()                       \
  do {                              \
    FENCE();                        \
    __builtin_amdgcn_s_barrier();   \
    FENCE();                        \
  } while (0)
#define LGKM0()                                       \
  do {                                                \
    asm volatile("s_waitcnt lgkmcnt(0)" ::: "memory");\
    __builtin_amdgcn_sched_barrier(0);                \
  } while (0)
#define VMC(n) asm volatile("s_waitcnt vmcnt(" #n ")" ::: "memory")

// -------------------- 256x256 8-phase bf16 GEMM, B transposed --------------
// (K-loop structure identical to round-2/round-8 verified kernel)
#define RD_A(cb, qm)                                                     \
  {                                                                      \
    _Pragma("unroll") for (int f_ = 0; f_ < 4; f_++) {                   \
      _Pragma("unroll") for (int ks_ = 0; ks_ < 2; ks_++) {              \
        Ar[f_][ks_] = *(const short8*)(ldsb + (cb) * 65536 +             \
            (wm * 128 + (qm) * 64 + f_ * 16 + r15) * 128 +               \
            (((ks_ * 4 + l4) ^ lx) << 4));                               \
      }                                                                  \
    }                                                                    \
  }

#define RD_B(cb, qn, Brg)                                                \
  {                                                                      \
    _Pragma("unroll") for (int g_ = 0; g_ < 2; g_++) {                   \
      _Pragma("unroll") for (int ks_ = 0; ks_ < 2; ks_++) {              \
        Brg[g_][ks_] = *(const short8*)(ldsb + (cb) * 65536 + 32768 +    \
            (wn * 64 + (qn) * 32 + g_ * 16 + r15) * 128 +                \
            (((ks_ * 4 + l4) ^ lx) << 4));                               \
      }                                                                  \
    }                                                                    \
  }

#define MM(qm, qn, B)                                                    \
  {                                                                      \
    _Pragma("unroll") for (int f_ = 0; f_ < 4; f_++) {                   \
      _Pragma("unroll") for (int g_ = 0; g_ < 2; g_++) {                 \
        acc[(qm) * 4 + f_][(qn) * 2 + g_] =                              \
            __builtin_amdgcn_mfma_f32_16x16x32_bf16(                     \
                Ar[f_][0], B[g_][0], acc[(qm) * 4 + f_][(qn) * 2 + g_],  \
                0, 0, 0);                                                \
        acc[(qm) * 4 + f_][(qn) * 2 + g_] =                              \
            __builtin_amdgcn_mfma_f32_16x16x32_bf16(                     \
                Ar[f_][1], B[g_][1], acc[(qm) * 4 + f_][(qn) * 2 + g_],  \
                0, 0, 0);                                                \
      }                                                                  \
    }                                                                    \
  }

template <bool OUT_BF16, bool ROPEQ>
__global__ __launch_bounds__(512, 2) void gemm256_8ph(
    const __hip_bfloat16* __restrict__ A, const __hip_bfloat16* __restrict__ Bt,
    void* __restrict__ C, int Nsplit, int ldc,
    void* __restrict__ C2, int ldc2, int N2,
    int K, int lda, int nbx,
    const float2* __restrict__ rtab, int t0q) {
  __shared__ __hip_bfloat16 lds[2][2][16384];  // [buf][A|B][256*64]
  const int tid = threadIdx.x;
  const int lane = tid & 63;
  const int wave = tid >> 6;
  const int wm = wave >> 2;  // 0..1
  const int wn = wave & 3;   // 0..3
  const int r15 = lane & 15;
  const int l4 = lane >> 4;
  const int lx = lane & 7;

  // XCD-chunked block swizzle (bijective when gridDim %8 == 0).
  const int nwg = gridDim.x;
  int wg = blockIdx.x;
  if ((nwg & 7) == 0) wg = (wg & 7) * (nwg >> 3) + (wg >> 3);
  const int by = wg / nbx;
  const int bx = wg - by * nbx;
  const int m0 = by * 256;
  const int n0 = bx * 256;

  const int lr0 = tid >> 3;
  const int sg0 = (tid & 7) ^ (lr0 & 7);
  const __hip_bfloat16* aSrc = A + (size_t)(m0 + lr0) * lda + sg0 * 8;
  const __hip_bfloat16* bSrc = Bt + (size_t)(n0 + lr0) * (size_t)K + sg0 * 8;

  auto stageA = [&](int cb, int h, int kt) {
#pragma unroll
    for (int i = 0; i < 2; i++) {
      const __hip_bfloat16* src = aSrc + (size_t)((h * 128 + i * 64) * lda + kt);
      __builtin_amdgcn_global_load_lds(
          (const __attribute__((address_space(1))) void*)src,
          (__attribute__((address_space(3))) void*)&lds[cb][0]
              [h * 8192 + (i * 512 + tid) * 8],
          16, 0, 0);
    }
  };
  auto stageB = [&](int cb, int h, int kt) {
#pragma unroll
    for (int i = 0; i < 2; i++) {
      const __hip_bfloat16* src = bSrc + (size_t)((h * 128 + i * 64) * K + kt);
      __builtin_amdgcn_global_load_lds(
          (const __attribute__((address_space(1))) void*)src,
          (__attribute__((address_space(3))) void*)&lds[cb][1]
              [h * 8192 + (i * 512 + tid) * 8],
          16, 0, 0);
    }
  };

  floatx4 acc[8][4] = {};
  short8 Ar[4][2], Br0[2][2], Br1[2][2];
  const char* ldsb = (const char*)&lds[0][0][0];

  // Prologue: buf0 = tile0 (B then A), buf1.B = tile1. 12 loads/thread.
  stageB(0, 0, 0); stageB(0, 1, 0);
  stageA(0, 0, 0); stageA(0, 1, 0);
  stageB(1, 0, 64); stageB(1, 1, 64);
  VMC(4);
  BAR();

  const int niter = K >> 7;
#pragma unroll 1
  for (int it = 0; it < niter; ++it) {
    const int ktc = it * 128;
    const int kt1 = ktc + 64;
    const int t0n = (ktc + 128 < K) ? ktc + 128 : 0;
    const int t1n = (ktc + 192 < K) ? ktc + 192 : 0;

    RD_A(0, 0); RD_B(0, 0, Br0);
    stageA(1, 0, kt1);
    BAR(); LGKM0();
    __builtin_amdgcn_s_setprio(1); MM(0, 0, Br0); __builtin_amdgcn_s_setprio(0);
    BAR();
    RD_B(0, 1, Br1);
    stageA(1, 1, kt1);
    BAR(); LGKM0();
    __builtin_amdgcn_s_setprio(1); MM(0, 1, Br1); __builtin_amdgcn_s_setprio(0);
    BAR();
    RD_A(0, 1);
    stageB(0, 0, t0n);
    BAR(); LGKM0();
    __builtin_amdgcn_s_setprio(1); MM(1, 1, Br1); __builtin_amdgcn_s_setprio(0);
    BAR();
    stageB(0, 1, t0n);
    BAR();
    __builtin_amdgcn_s_setprio(1); MM(1, 0, Br0); __builtin_amdgcn_s_setprio(0);
    VMC(4);
    BAR();
    RD_A(1, 0); RD_B(1, 0, Br0);
    stageA(0, 0, t0n);
    BAR(); LGKM0();
    __builtin_amdgcn_s_setprio(1); MM(0, 0, Br0); __builtin_amdgcn_s_setprio(0);
    BAR();
    RD_B(1, 1, Br1);
    stageA(0, 1, t0n);
    BAR(); LGKM0();
    __builtin_amdgcn_s_setprio(1); MM(0, 1, Br1); __builtin_amdgcn_s_setprio(0);
    BAR();
    RD_A(1, 1);
    stageB(1, 0, t1n);
    BAR(); LGKM0();
    __builtin_amdgcn_s_setprio(1); MM(1, 1, Br1); __builtin_amdgcn_s_setprio(0);
    BAR();
    stageB(1, 1, t1n);
    BAR();
    __builtin_amdgcn_s_setprio(1); MM(1, 0, Br0); __builtin_amdgcn_s_setprio(0);
    VMC(4);
    BAR();
  }
  VMC(0);

  // Epilogue. Optional fused RoPE-on-q: each head's rope window
  // [192h+128, 192h+192) is 64-aligned and equals one wn group; the pair
  // (i, i+32) lives in acc[f][g] and acc[f][g+2] of the same wave.
  const int crow = l4 * 4;
  bool inwin = false;
  int hh_ = 0;
  if (ROPEQ) {
    const int cblk = n0 + wn * 64;
    inwin = (cblk % 192) == 128;
    hh_ = cblk / 192;
  }
#pragma unroll
  for (int f = 0; f < 8; f++) {
    if (ROPEQ && inwin) {
#pragma unroll
      for (int g = 0; g < 2; g++) {
        const int i = g * 16 + r15;  // 0..31
#pragma unroll
        for (int r = 0; r < 4; r++) {
          const int row = m0 + wm * 128 + f * 16 + crow + r;
          const int p = ((((t0q + row) & 4095) * 16 + hh_) & 4095);
          const float2 cs = rtab[p * 32 + i];
          const float x1 = acc[f][g][r];
          const float x2 = acc[f][g + 2][r];
          acc[f][g][r] = x1 * cs.x - x2 * cs.y;
          acc[f][g + 2][r] = x2 * cs.x + x1 * cs.y;
        }
      }
    }
#pragma unroll
    for (int g = 0; g < 4; g++) {
      const int col = n0 + wn * 64 + g * 16 + r15;
      if (col < Nsplit) {
#pragma unroll
        for (int r = 0; r < 4; r++) {
          const size_t row = (size_t)(m0 + wm * 128 + f * 16 + crow + r);
          if (OUT_BF16)
            ((__hip_bfloat16*)C)[row * ldc + col] =
                __float2bfloat16(acc[f][g][r]);
          else
            ((float*)C)[row * ldc + col] = acc[f][g][r];
        }
      } else if (col - Nsplit < N2) {
        const int c2 = col - Nsplit;
#pragma unroll
        for (int r = 0; r < 4; r++) {
          const size_t row = (size_t)(m0 + wm * 128 + f * 16 + crow + r);
          if (OUT_BF16)
            ((__hip_bfloat16*)C2)[row * ldc2 + c2] =
                __float2bfloat16(acc[f][g][r]);
          else
            ((float*)C2)[row * ldc2 + c2] = acc[f][g][r];
        }
      }
    }
  }
}

// -------------------- weight transpose + cast ------------------------------
__global__ __launch_bounds__(256) void transpose_cast(
    const float* __restrict__ in, __hip_bfloat16* __restrict__ out, int K,
    int N) {
  __shared__ float tile[32][33];
  const int n0 = blockIdx.x * 32, k0 = blockIdx.y * 32;
  const int tx = threadIdx.x & 31, ty = threadIdx.x >> 5;
#pragma unroll
  for (int r = 0; r < 32; r += 8) {
    const int k = k0 + ty + r, n = n0 + tx;
    tile[ty + r][tx] = (n < N) ? in[(size_t)k * N + n] : 0.f;
  }
  __syncthreads();
#pragma unroll
  for (int r = 0; r < 32; r += 8) {
    const int n = n0 + ty + r, k = k0 + tx;
    out[(size_t)n * K + k] = __float2bfloat16(tile[tx][ty + r]);
  }
}

// -------------------- x cast (8 elems/thread, packed short8 store) ---------
__global__ __launch_bounds__(256) void cast_f32_bf16(
    const float* __restrict__ in, __hip_bfloat16* __restrict__ out) {
  const size_t i = ((size_t)blockIdx.x * 256 + threadIdx.x) * 8;
  const float4 v0 = *(const float4*)(in + i);
  const float4 v1 = *(const float4*)(in + i + 4);
  const float f[8] = {v0.x, v0.y, v0.z, v0.w, v1.x, v1.y, v1.z, v1.w};
  short8 o;
#pragma unroll
  for (int k = 0; k < 8; k++) {
    const __hip_bfloat16 b = __float2bfloat16(f[k]);
    o[k] = *(const short*)&b;
  }
  *(short8*)(out + i) = o;
}

// -------------------- RMSNorm (bf16 in-place, short8 vectorized) -----------
__global__ __launch_bounds__(256) void rmsnorm_bf16(
    __hip_bfloat16* __restrict__ x, const float* __restrict__ w, int ncols,
    int stride) {
  __hip_bfloat16* xr = x + (size_t)blockIdx.x * stride;
  float ss = 0.f;
  for (int c = threadIdx.x * 8; c < ncols; c += 2048) {
    const short8 v = *(const short8*)(xr + c);
#pragma unroll
    for (int k = 0; k < 8; k++) {
      const float f = bfbits2f((unsigned short)v[k]);
      ss += f * f;
    }
  }
#pragma unroll
  for (int off = 32; off > 0; off >>= 1) ss += __shfl_down(ss, off);
  __shared__ float wsum[4];
  __shared__ float scale_sh;
  const int wv = threadIdx.x >> 6, lane = threadIdx.x & 63;
  if (lane == 0) wsum[wv] = ss;
  __syncthreads();
  if (threadIdx.x == 0) {
    const float tot = wsum[0] + wsum[1] + wsum[2] + wsum[3];
    scale_sh = rsqrtf(tot / (float)ncols + 1e-6f);
  }
  __syncthreads();
  const float scale = scale_sh;
  for (int c = threadIdx.x * 8; c < ncols; c += 2048) {
    const short8 v = *(const short8*)(xr + c);
    short8 o;
#pragma unroll
    for (int k = 0; k < 8; k++) {
      float f = bfbits2f((unsigned short)v[k]) * scale;
      if (w) f *= w[c + k];
      const __hip_bfloat16 b = __float2bfloat16(f);
      o[k] = *(const short*)&b;
    }
    *(short8*)(xr + c) = o;
  }
}

// -------------------- RoPE cos/sin table (double math, once per (pos,i)) ---
__global__ __launch_bounds__(256) void build_rope_tab(
    float2* __restrict__ tab, const int* __restrict__ start_pos_p) {
  const int idx = blockIdx.x * 256 + threadIdx.x;  // 4096*32
  const int i = idx & 31;
  const int p = idx >> 5;
  const int pos = p + start_pos_p[0];
  const double theta = pow(10000.0, -(double)i / 32.0);
  const double ang = (double)pos * theta;
  tab[idx] = make_float2((float)cos(ang), (float)sin(ang));
}

// -------------------- fused RoPE(k_pe) + RMSNorm(kv_c) ---------------------
__global__ __launch_bounds__(128) void rope_rms_kv(
    __hip_bfloat16* __restrict__ kv, const float2* __restrict__ tab) {
  __hip_bfloat16* xr = kv + (size_t)blockIdx.x * 576;
  const int tid = threadIdx.x;
  __shared__ float scale_sh;
  float ss = 0.f;
  short8 v;
  if (tid < 64) {
    v = *(const short8*)(xr + tid * 8);
#pragma unroll
    for (int k = 0; k < 8; k++) {
      const float f = bfbits2f((unsigned short)v[k]);
      ss += f * f;
    }
  } else if (tid < 96) {
    const int i = tid - 64;
    const float2 cs = tab[i];
    __hip_bfloat16* base = xr + 512;
    const float x1 = __bfloat162float(base[i]);
    const float x2 = __bfloat162float(base[i + 32]);
    base[i] = __float2bfloat16(x1 * cs.x - x2 * cs.y);
    base[i + 32] = __float2bfloat16(x2 * cs.x + x1 * cs.y);
  }
#pragma unroll
  for (int off = 32; off > 0; off >>= 1) ss += __shfl_down(ss, off);
  if (tid == 0) scale_sh = rsqrtf(ss / 512.f + 1e-6f);
  __syncthreads();
  if (tid < 64) {
    const float scale = scale_sh;
    short8 o;
#pragma unroll
    for (int k = 0; k < 8; k++) {
      const __hip_bfloat16 b =
          __float2bfloat16(bfbits2f((unsigned short)v[k]) * scale);
      o[k] = *(const short*)&b;
    }
    *(short8*)(xr + tid * 8) = o;
  }
}

// -------------------- wave-per-token attention (MFMA QK^T, V direct) -------
__global__ __launch_bounds__(256) void attn_wave_token(
    const __hip_bfloat16* __restrict__ q,     // [T][16][192]
    const __hip_bfloat16* __restrict__ kvup,  // [T][16][256] (k_nope|v)
    const __hip_bfloat16* __restrict__ kv,    // [T][576], k_pe at +512
    __hip_bfloat16* __restrict__ ctx) {       // [T][16][128]
  __shared__ __hip_bfloat16 sq[4][16 * 200];
  __shared__ __hip_bfloat16 su[4][16 * 136];  // k_nope only, +8 pad
  __shared__ __hip_bfloat16 skpe[4][64];
  __shared__ float sp[4][16][20];  // padded: rows 80B (16B-aligned float4)
  const int tid = threadIdx.x;
  const int w = tid >> 6;
  const int lane = tid & 63;
  const int t = blockIdx.x * 4 + w;

  const __hip_bfloat16* qb = q + (size_t)t * 3072;
  const __hip_bfloat16* ub = kvup + (size_t)t * 4096;
#pragma unroll
  for (int i = 0; i < 6; i++) {
    const int u = lane + 64 * i;  // u < 384
    const int row = u / 24;
    *(short8*)(&sq[w][u * 8 + row * 8]) = *(const short8*)(qb + u * 8);
  }
#pragma unroll
  for (int i = 0; i < 4; i++) {
    const int u = lane + 64 * i;  // u < 256
    const int row = u >> 4;
    *(short8*)(&su[w][u * 8 + row * 8]) =
        *(const short8*)(ub + row * 256 + (u & 15) * 8);
  }
  if (lane < 8)
    *(short8*)(&skpe[w][lane * 8]) =
        *(const short8*)(kv + (size_t)t * 576 + 512 + lane * 8);
  __syncthreads();

  const int r15 = lane & 15;
  const int l4 = lane >> 4;

  // ---- QK^T via MFMA: 4 slices from k_nope + 2 from k_pe (broadcast) ----
  floatx4 sacc = {0.f, 0.f, 0.f, 0.f};
#pragma unroll
  for (int ks = 0; ks < 4; ks++) {
    const short8 aq = *(const short8*)(&sq[w][r15 * 200 + ks * 32 + l4 * 8]);
    const short8 bk = *(const short8*)(&su[w][r15 * 136 + ks * 32 + l4 * 8]);
    sacc = __builtin_amdgcn_mfma_f32_16x16x32_bf16(aq, bk, sacc, 0, 0, 0);
  }
#pragma unroll
  for (int ks = 4; ks < 6; ks++) {
    const short8 aq = *(const short8*)(&sq[w][r15 * 200 + ks * 32 + l4 * 8]);
    const short8 bk = *(const short8*)(&skpe[w][(ks - 4) * 32 + l4 * 8]);
    sacc = __builtin_amdgcn_mfma_f32_16x16x32_bf16(aq, bk, sacc, 0, 0, 0);
  }

  // ---- V loads (global, L3-resident; issued early to hide latency) ----
  const int d0 = (lane & 31) * 4;
  float vreg[16][4];
#pragma unroll
  for (int j = 0; j < 16; j++) {
    const short4x v4 = *(const short4x*)(ub + j * 256 + 128 + d0);
#pragma unroll
    for (int k = 0; k < 4; k++) vreg[j][k] = bfbits2f((unsigned short)v4[k]);
  }

  // ---- softmax over kh: lane holds S[4*l4+reg][r15]; reduce over r15 ----
  const float scale = 0.07216878364870323f;  // 1/sqrt(192)
  float sv4[4];
#pragma unroll
  for (int r = 0; r < 4; r++) sv4[r] = sacc[r] * scale;
  float mx[4];
#pragma unroll
  for (int r = 0; r < 4; r++) {
    float m = sv4[r];
    m = fmaxf(m, __shfl_xor(m, 1));
    m = fmaxf(m, __shfl_xor(m, 2));
    m = fmaxf(m, __shfl_xor(m, 4));
    m = fmaxf(m, __shfl_xor(m, 8));
    mx[r] = m;
  }
  float e[4];
#pragma unroll
  for (int r = 0; r < 4; r++) {
    e[r] = expf(sv4[r] - mx[r]);
    float s = e[r];
    s += __shfl_xor(s, 1);
    s += __shfl_xor(s, 2);
    s += __shfl_xor(s, 4);
    s += __shfl_xor(s, 8);
    e[r] *= (1.0f / s);
  }
#pragma unroll
  for (int r = 0; r < 4; r++) sp[w][l4 * 4 + r][r15] = e[r];
  __syncthreads();

  // ---- PV (VALU): ctx[hh][d0..d0+3] = sum_j P[hh][j] * V[j][d0..d0+3] ----
  const int hb = (lane >> 5) * 8;
  __hip_bfloat16* cb = ctx + (size_t)t * 2048;
#pragma unroll
  for (int g = 0; g < 8; g++) {
    const int hh = hb + g;
    float o[4] = {0.f, 0.f, 0.f, 0.f};
#pragma unroll
    for (int j4 = 0; j4 < 4; j4++) {
      const float4 p4 = *(const float4*)(&sp[w][hh][j4 * 4]);
      const float pj[4] = {p4.x, p4.y, p4.z, p4.w};
#pragma unroll
      for (int jj = 0; jj < 4; jj++) {
        const int j = j4 * 4 + jj;
#pragma unroll
        for (int k = 0; k < 4; k++) o[k] += pj[jj] * vreg[j][k];
      }
    }
    short4x st;
#pragma unroll
    for (int k = 0; k < 4; k++) {
      const __hip_bfloat16 b = __float2bfloat16(o[k]);
      st[k] = *(const short*)&b;
    }
    *(short4x*)(cb + hh * 128 + d0) = st;
  }
}

// ---------------------------------------------------------------------------
extern "C" void kernel_launch(void* const* d_in, const int* in_sizes, int n_in,
                              void* d_out, int out_size, void* d_ws,
                              size_t ws_size, hipStream_t stream) {
  const float* x = (const float*)d_in[0];          // 16384 x 2048
  const float* wq_a = (const float*)d_in[1];       // 2048 x 1536
  const float* q_norm_w = (const float*)d_in[2];   // 1536
  const float* wq_b = (const float*)d_in[3];       // 1536 x 3072
  const float* wkv_a = (const float*)d_in[4];      // 2048 x 576
  const float* wkv_b = (const float*)d_in[5];      // 512 x 4096
  const float* wo = (const float*)d_in[6];         // 2048 x 2048
  const int* start_pos = (const int*)d_in[7];
  float* out = (float*)d_out;

  const int T = 16384;
  __hip_bfloat16* w0 = (__hip_bfloat16*)d_ws;
  __hip_bfloat16* wqkv_aT = w0;                      // 2304 x 2048
  __hip_bfloat16* wq_aT = wqkv_aT;                   // rows 0..1535
  __hip_bfloat16* wkv_aT = wqkv_aT + 1536 * 2048;    // rows 1536..2303 (pad)
  __hip_bfloat16* wq_bT = wqkv_aT + 2304 * 2048;     // 3072 x 1536
  __hip_bfloat16* wkv_bT = wq_bT + 3072 * 1536;      // 4096 x 512
  __hip_bfloat16* woT = wkv_bT + 4096 * 512;         // 2048 x 2048
  float2* rope_tab = (float2*)(woT + 2048 * 2048);   // 4096 x 32 float2 (1MB)
  __hip_bfloat16* chunk0 = (__hip_bfloat16*)(rope_tab + 4096 * 32);
  const size_t w_bytes = (size_t)((char*)chunk0 - (char*)w0);

  const size_t per_tok = 11840 * sizeof(__hip_bfloat16);
  int Tc = T;
  while (Tc > 256 && w_bytes + (size_t)Tc * per_tok > ws_size) Tc >>= 1;

  __hip_bfloat16* xb = chunk0;                       // Tc x 2048
  __hip_bfloat16* q_buf = xb + (size_t)Tc * 2048;    // Tc x 3072
  __hip_bfloat16* kvup = q_buf + (size_t)Tc * 3072;  // Tc x 4096
  __hip_bfloat16* cbuf = kvup + (size_t)Tc * 4096;   // Tc x 2048
  __hip_bfloat16* kv = cbuf + (size_t)Tc * 2048;     // Tc x 576

  dim3 blk(256);
  dim3 blk512(512);

  transpose_cast<<<dim3(1536 / 32, 2048 / 32), blk, 0, stream>>>(wq_a, wq_aT,
                                                                 2048, 1536);
  transpose_cast<<<dim3(768 / 32, 2048 / 32), blk, 0, stream>>>(wkv_a, wkv_aT,
                                                                2048, 576);
  transpose_cast<<<dim3(3072 / 32, 1536 / 32), blk, 0, stream>>>(wq_b, wq_bT,
                                                                 1536, 3072);
  transpose_cast<<<dim3(4096 / 32, 512 / 32), blk, 0, stream>>>(wkv_b, wkv_bT,
                                                                512, 4096);
  transpose_cast<<<dim3(2048 / 32, 2048 / 32), blk, 0, stream>>>(wo, woT, 2048,
                                                                 2048);
  build_rope_tab<<<(4096 * 32) / 256, blk, 0, stream>>>(rope_tab, start_pos);

  const int nby = Tc / 256;
  for (int t0 = 0; t0 < T; t0 += Tc) {
    cast_f32_bf16<<<(Tc * 2048) / 2048, blk, 0, stream>>>(
        x + (size_t)t0 * 2048, xb);
    // G1+G3 fused: [q_lora | kv] = xb @ [wq_a | wkv_a]^T
    gemm256_8ph<true, false><<<dim3(9 * nby), blk512, 0, stream>>>(
        xb, wqkv_aT, cbuf, 1536, 1536, kv, 576, 576, 2048, 2048, 9,
        nullptr, 0);
    rmsnorm_bf16<<<Tc, blk, 0, stream>>>(cbuf, q_norm_w, 1536, 1536);
    rope_rms_kv<<<Tc, dim3(128), 0, stream>>>(kv, rope_tab);
    // G2: q = q_lora @ wq_b^T, rope_q fused into epilogue
    gemm256_8ph<true, true><<<dim3(12 * nby), blk512, 0, stream>>>(
        cbuf, wq_bT, q_buf, 3072, 3072, nullptr, 0, 0, 1536, 1536, 12,
        rope_tab, t0);
    // G4: kvup = kvn @ wkv_b^T (A ld 576, K=512)
    gemm256_8ph<true, false><<<dim3(16 * nby), blk512, 0, stream>>>(
        kv, wkv_bT, kvup, 4096, 4096, nullptr, 0, 0, 512, 576, 16,
        nullptr, 0);
    // attention -> ctx (reuses cbuf)
    attn_wave_token<<<Tc / 4, blk, 0, stream>>>(q_buf, kvup, kv, cbuf);
    // G5: out = ctx @ wo^T (fp32 out)
    gemm256_8ph<false, false><<<dim3(8 * nby), blk512, 0, stream>>>(
        cbuf, woT, out + (size_t)t0 * 2048, 2048, 2048, nullptr, 0, 0, 2048,
        2048, 8, nullptr, 0);
  }
}

// Round 12
// 855.649 us; speedup vs baseline: 1.0919x; 1.0607x over previous
//
#include <hip/hip_runtime.h>
#include <hip/hip_bf16.h>
#include <math.h>

// ---------------------------------------------------------------------------
// MLA forward. GEMMs: 256x256 8-phase MFMA schedule (T2 swizzle + counted
// vmcnt + setprio), 16x16x32 MFMA — round-2/round-8 verified schedule.
// RoPE table; G1+G3 fused; rope_q fused into G2 epilogue; attention QK^T on
// MFMA with V direct from global. r12: all independent small kernels merged
// into two branch-ladder dispatches (prep_all, post_g1g3) to eliminate
// serialized launch gaps + idle tails.
// ---------------------------------------------------------------------------

typedef __attribute__((ext_vector_type(8))) short short8;
typedef __attribute__((ext_vector_type(4))) short short4x;
typedef __attribute__((ext_vector_type(4))) float floatx4;

__device__ inline float bfbits2f(unsigned short u) {
  union { unsigned int i; float f; } c;
  c.i = ((unsigned int)u) << 16;
  return c.f;
}

#define FENCE() asm volatile("" ::: "memory")
#define BAR()                       \
  do {                              \
    FENCE();                        \
    __builtin_amdgcn_s_barrier();   \
    FENCE();                        \
  } while (0)
#define LGKM0()                                       \
  do {                                                \
    asm volatile("s_waitcnt lgkmcnt(0)" ::: "memory");\
    __builtin_amdgcn_sched_barrier(0);                \
  } while (0)
#define VMC(n) asm volatile("s_waitcnt vmcnt(" #n ")" ::: "memory")

// -------------------- 256x256 8-phase bf16 GEMM, B transposed --------------
#define RD_A(cb, qm)                                                     \
  {                                                                      \
    _Pragma("unroll") for (int f_ = 0; f_ < 4; f_++) {                   \
      _Pragma("unroll") for (int ks_ = 0; ks_ < 2; ks_++) {              \
        Ar[f_][ks_] = *(const short8*)(ldsb + (cb) * 65536 +             \
            (wm * 128 + (qm) * 64 + f_ * 16 + r15) * 128 +               \
            (((ks_ * 4 + l4) ^ lx) << 4));                               \
      }                                                                  \
    }                                                                    \
  }

#define RD_B(cb, qn, Brg)                                                \
  {                                                                      \
    _Pragma("unroll") for (int g_ = 0; g_ < 2; g_++) {                   \
      _Pragma("unroll") for (int ks_ = 0; ks_ < 2; ks_++) {              \
        Brg[g_][ks_] = *(const short8*)(ldsb + (cb) * 65536 + 32768 +    \
            (wn * 64 + (qn) * 32 + g_ * 16 + r15) * 128 +                \
            (((ks_ * 4 + l4) ^ lx) << 4));                               \
      }                                                                  \
    }                                                                    \
  }

#define MM(qm, qn, B)                                                    \
  {                                                                      \
    _Pragma("unroll") for (int f_ = 0; f_ < 4; f_++) {                   \
      _Pragma("unroll") for (int g_ = 0; g_ < 2; g_++) {                 \
        acc[(qm) * 4 + f_][(qn) * 2 + g_] =                              \
            __builtin_amdgcn_mfma_f32_16x16x32_bf16(                     \
                Ar[f_][0], B[g_][0], acc[(qm) * 4 + f_][(qn) * 2 + g_],  \
                0, 0, 0);                                                \
        acc[(qm) * 4 + f_][(qn) * 2 + g_] =                              \
            __builtin_amdgcn_mfma_f32_16x16x32_bf16(                     \
                Ar[f_][1], B[g_][1], acc[(qm) * 4 + f_][(qn) * 2 + g_],  \
                0, 0, 0);                                                \
      }                                                                  \
    }                                                                    \
  }

template <bool OUT_BF16, bool ROPEQ>
__global__ __launch_bounds__(512, 2) void gemm256_8ph(
    const __hip_bfloat16* __restrict__ A, const __hip_bfloat16* __restrict__ Bt,
    void* __restrict__ C, int Nsplit, int ldc,
    void* __restrict__ C2, int ldc2, int N2,
    int K, int lda, int nbx,
    const float2* __restrict__ rtab, int t0q) {
  __shared__ __hip_bfloat16 lds[2][2][16384];  // [buf][A|B][256*64]
  const int tid = threadIdx.x;
  const int lane = tid & 63;
  const int wave = tid >> 6;
  const int wm = wave >> 2;  // 0..1
  const int wn = wave & 3;   // 0..3
  const int r15 = lane & 15;
  const int l4 = lane >> 4;
  const int lx = lane & 7;

  // XCD-chunked block swizzle (bijective when gridDim %8 == 0).
  const int nwg = gridDim.x;
  int wg = blockIdx.x;
  if ((nwg & 7) == 0) wg = (wg & 7) * (nwg >> 3) + (wg >> 3);
  const int by = wg / nbx;
  const int bx = wg - by * nbx;
  const int m0 = by * 256;
  const int n0 = bx * 256;

  const int lr0 = tid >> 3;
  const int sg0 = (tid & 7) ^ (lr0 & 7);
  const __hip_bfloat16* aSrc = A + (size_t)(m0 + lr0) * lda + sg0 * 8;
  const __hip_bfloat16* bSrc = Bt + (size_t)(n0 + lr0) * (size_t)K + sg0 * 8;

  auto stageA = [&](int cb, int h, int kt) {
#pragma unroll
    for (int i = 0; i < 2; i++) {
      const __hip_bfloat16* src = aSrc + (size_t)((h * 128 + i * 64) * lda + kt);
      __builtin_amdgcn_global_load_lds(
          (const __attribute__((address_space(1))) void*)src,
          (__attribute__((address_space(3))) void*)&lds[cb][0]
              [h * 8192 + (i * 512 + tid) * 8],
          16, 0, 0);
    }
  };
  auto stageB = [&](int cb, int h, int kt) {
#pragma unroll
    for (int i = 0; i < 2; i++) {
      const __hip_bfloat16* src = bSrc + (size_t)((h * 128 + i * 64) * K + kt);
      __builtin_amdgcn_global_load_lds(
          (const __attribute__((address_space(1))) void*)src,
          (__attribute__((address_space(3))) void*)&lds[cb][1]
              [h * 8192 + (i * 512 + tid) * 8],
          16, 0, 0);
    }
  };

  floatx4 acc[8][4] = {};
  short8 Ar[4][2], Br0[2][2], Br1[2][2];
  const char* ldsb = (const char*)&lds[0][0][0];

  // Prologue: buf0 = tile0 (B then A), buf1.B = tile1. 12 loads/thread.
  stageB(0, 0, 0); stageB(0, 1, 0);
  stageA(0, 0, 0); stageA(0, 1, 0);
  stageB(1, 0, 64); stageB(1, 1, 64);
  VMC(4);
  BAR();

  const int niter = K >> 7;
#pragma unroll 1
  for (int it = 0; it < niter; ++it) {
    const int ktc = it * 128;
    const int kt1 = ktc + 64;
    const int t0n = (ktc + 128 < K) ? ktc + 128 : 0;
    const int t1n = (ktc + 192 < K) ? ktc + 192 : 0;

    RD_A(0, 0); RD_B(0, 0, Br0);
    stageA(1, 0, kt1);
    BAR(); LGKM0();
    __builtin_amdgcn_s_setprio(1); MM(0, 0, Br0); __builtin_amdgcn_s_setprio(0);
    BAR();
    RD_B(0, 1, Br1);
    stageA(1, 1, kt1);
    BAR(); LGKM0();
    __builtin_amdgcn_s_setprio(1); MM(0, 1, Br1); __builtin_amdgcn_s_setprio(0);
    BAR();
    RD_A(0, 1);
    stageB(0, 0, t0n);
    BAR(); LGKM0();
    __builtin_amdgcn_s_setprio(1); MM(1, 1, Br1); __builtin_amdgcn_s_setprio(0);
    BAR();
    stageB(0, 1, t0n);
    BAR();
    __builtin_amdgcn_s_setprio(1); MM(1, 0, Br0); __builtin_amdgcn_s_setprio(0);
    VMC(4);
    BAR();
    RD_A(1, 0); RD_B(1, 0, Br0);
    stageA(0, 0, t0n);
    BAR(); LGKM0();
    __builtin_amdgcn_s_setprio(1); MM(0, 0, Br0); __builtin_amdgcn_s_setprio(0);
    BAR();
    RD_B(1, 1, Br1);
    stageA(0, 1, t0n);
    BAR(); LGKM0();
    __builtin_amdgcn_s_setprio(1); MM(0, 1, Br1); __builtin_amdgcn_s_setprio(0);
    BAR();
    RD_A(1, 1);
    stageB(1, 0, t1n);
    BAR(); LGKM0();
    __builtin_amdgcn_s_setprio(1); MM(1, 1, Br1); __builtin_amdgcn_s_setprio(0);
    BAR();
    stageB(1, 1, t1n);
    BAR();
    __builtin_amdgcn_s_setprio(1); MM(1, 0, Br0); __builtin_amdgcn_s_setprio(0);
    VMC(4);
    BAR();
  }
  VMC(0);

  // Epilogue (+ optional fused RoPE-on-q; window = one wn group; pair
  // (i, i+32) = acc[f][g] <-> acc[f][g+2] of the same wave).
  const int crow = l4 * 4;
  bool inwin = false;
  int hh_ = 0;
  if (ROPEQ) {
    const int cblk = n0 + wn * 64;
    inwin = (cblk % 192) == 128;
    hh_ = cblk / 192;
  }
#pragma unroll
  for (int f = 0; f < 8; f++) {
    if (ROPEQ && inwin) {
#pragma unroll
      for (int g = 0; g < 2; g++) {
        const int i = g * 16 + r15;  // 0..31
#pragma unroll
        for (int r = 0; r < 4; r++) {
          const int row = m0 + wm * 128 + f * 16 + crow + r;
          const int p = ((((t0q + row) & 4095) * 16 + hh_) & 4095);
          const float2 cs = rtab[p * 32 + i];
          const float x1 = acc[f][g][r];
          const float x2 = acc[f][g + 2][r];
          acc[f][g][r] = x1 * cs.x - x2 * cs.y;
          acc[f][g + 2][r] = x2 * cs.x + x1 * cs.y;
        }
      }
    }
#pragma unroll
    for (int g = 0; g < 4; g++) {
      const int col = n0 + wn * 64 + g * 16 + r15;
      if (col < Nsplit) {
#pragma unroll
        for (int r = 0; r < 4; r++) {
          const size_t row = (size_t)(m0 + wm * 128 + f * 16 + crow + r);
          if (OUT_BF16)
            ((__hip_bfloat16*)C)[row * ldc + col] =
                __float2bfloat16(acc[f][g][r]);
          else
            ((float*)C)[row * ldc + col] = acc[f][g][r];
        }
      } else if (col - Nsplit < N2) {
        const int c2 = col - Nsplit;
#pragma unroll
        for (int r = 0; r < 4; r++) {
          const size_t row = (size_t)(m0 + wm * 128 + f * 16 + crow + r);
          if (OUT_BF16)
            ((__hip_bfloat16*)C2)[row * ldc2 + c2] =
                __float2bfloat16(acc[f][g][r]);
          else
            ((float*)C2)[row * ldc2 + c2] = acc[f][g][r];
        }
      }
    }
  }
}

// -------------------- x cast (standalone: only for multi-chunk t0>0) -------
__global__ __launch_bounds__(256) void cast_f32_bf16(
    const float* __restrict__ in, __hip_bfloat16* __restrict__ out) {
  const size_t i = ((size_t)blockIdx.x * 256 + threadIdx.x) * 8;
  const float4 v0 = *(const float4*)(in + i);
  const float4 v1 = *(const float4*)(in + i + 4);
  const float f[8] = {v0.x, v0.y, v0.z, v0.w, v1.x, v1.y, v1.z, v1.w};
  short8 o;
#pragma unroll
  for (int k = 0; k < 8; k++) {
    const __hip_bfloat16 b = __float2bfloat16(f[k]);
    o[k] = *(const short*)&b;
  }
  *(short8*)(out + i) = o;
}

// -------------------- prep_all: cast + 5 transposes + rope table -----------
// All segments mutually independent (disjoint inputs/outputs). Segment
// layout: [0,ncast) cast | 3072 wq_a | 1536 wkv_a | 4608 wq_b | 2048 wkv_b
// | 4096 wo | 512 tab. Barriers are block-uniform (branch on blockIdx).
__global__ __launch_bounds__(256) void prep_all(
    const float* __restrict__ x, const float* __restrict__ wq_a,
    const float* __restrict__ wkv_a, const float* __restrict__ wq_b,
    const float* __restrict__ wkv_b, const float* __restrict__ wo,
    const int* __restrict__ start_pos_p,
    __hip_bfloat16* __restrict__ xb, __hip_bfloat16* __restrict__ wq_aT,
    __hip_bfloat16* __restrict__ wkv_aT, __hip_bfloat16* __restrict__ wq_bT,
    __hip_bfloat16* __restrict__ wkv_bT, __hip_bfloat16* __restrict__ woT,
    float2* __restrict__ tab, int ncast) {
  __shared__ float tile[32][33];
  const int tid = threadIdx.x;
  int bid = blockIdx.x;

  if (bid < ncast) {  // ---- cast x -> xb ----
    const size_t i = ((size_t)bid * 256 + tid) * 8;
    const float4 v0 = *(const float4*)(x + i);
    const float4 v1 = *(const float4*)(x + i + 4);
    const float f[8] = {v0.x, v0.y, v0.z, v0.w, v1.x, v1.y, v1.z, v1.w};
    short8 o;
#pragma unroll
    for (int k = 0; k < 8; k++) {
      const __hip_bfloat16 b = __float2bfloat16(f[k]);
      o[k] = *(const short*)&b;
    }
    *(short8*)(xb + i) = o;
    return;
  }
  bid -= ncast;

  const float* tin = nullptr;
  __hip_bfloat16* tout = nullptr;
  int K_ = 0, N_ = 0, nbx_ = 0;
  if (bid < 3072) {
    tin = wq_a; tout = wq_aT; K_ = 2048; N_ = 1536; nbx_ = 48;
  } else if (bid < 3072 + 1536) {
    bid -= 3072;
    tin = wkv_a; tout = wkv_aT; K_ = 2048; N_ = 576; nbx_ = 24;
  } else if (bid < 3072 + 1536 + 4608) {
    bid -= 3072 + 1536;
    tin = wq_b; tout = wq_bT; K_ = 1536; N_ = 3072; nbx_ = 96;
  } else if (bid < 3072 + 1536 + 4608 + 2048) {
    bid -= 3072 + 1536 + 4608;
    tin = wkv_b; tout = wkv_bT; K_ = 512; N_ = 4096; nbx_ = 128;
  } else if (bid < 3072 + 1536 + 4608 + 2048 + 4096) {
    bid -= 3072 + 1536 + 4608 + 2048;
    tin = wo; tout = woT; K_ = 2048; N_ = 2048; nbx_ = 64;
  } else {  // ---- rope table ----
    bid -= 3072 + 1536 + 4608 + 2048 + 4096;
    const int idx = bid * 256 + tid;  // < 4096*32
    const int i = idx & 31;
    const int p = idx >> 5;
    const int pos = p + start_pos_p[0];
    const double theta = pow(10000.0, -(double)i / 32.0);
    const double ang = (double)pos * theta;
    tab[idx] = make_float2((float)cos(ang), (float)sin(ang));
    return;
  }

  // ---- transpose+cast tile (body identical to r11 transpose_cast) ----
  const int bx = bid % nbx_, by = bid / nbx_;
  const int n0 = bx * 32, k0 = by * 32;
  const int tx = tid & 31, ty = tid >> 5;
#pragma unroll
  for (int r = 0; r < 32; r += 8) {
    const int k = k0 + ty + r, n = n0 + tx;
    tile[ty + r][tx] = (n < N_) ? tin[(size_t)k * N_ + n] : 0.f;
  }
  __syncthreads();
#pragma unroll
  for (int r = 0; r < 32; r += 8) {
    const int n = n0 + ty + r, k = k0 + tx;
    tout[(size_t)n * K_ + k] = __float2bfloat16(tile[tx][ty + r]);
  }
}

// -------------------- post_g1g3: rmsnorm(cbuf) + rope+rms(kv) --------------
// Segment [0,Tc): rmsnorm row of cbuf (ncols 1536, weight w).
// Segment [Tc,2Tc): fused rope(k_pe)+rmsnorm(kv_c) on kv row.
__global__ __launch_bounds__(256) void post_g1g3(
    __hip_bfloat16* __restrict__ cbuf, const float* __restrict__ w,
    __hip_bfloat16* __restrict__ kv, const float2* __restrict__ tab, int Tc) {
  const int tid = threadIdx.x;
  if ((int)blockIdx.x < Tc) {
    // ---- rmsnorm on cbuf row (body identical to r11 rmsnorm_bf16) ----
    __hip_bfloat16* xr = cbuf + (size_t)blockIdx.x * 1536;
    float ss = 0.f;
    for (int c = tid * 8; c < 1536; c += 2048) {
      const short8 v = *(const short8*)(xr + c);
#pragma unroll
      for (int k = 0; k < 8; k++) {
        const float f = bfbits2f((unsigned short)v[k]);
        ss += f * f;
      }
    }
#pragma unroll
    for (int off = 32; off > 0; off >>= 1) ss += __shfl_down(ss, off);
    __shared__ float wsum[4];
    __shared__ float scale_sh;
    const int wv = tid >> 6, lane = tid & 63;
    if (lane == 0) wsum[wv] = ss;
    __syncthreads();
    if (tid == 0) {
      const float tot = wsum[0] + wsum[1] + wsum[2] + wsum[3];
      scale_sh = rsqrtf(tot / 1536.f + 1e-6f);
    }
    __syncthreads();
    const float scale = scale_sh;
    for (int c = tid * 8; c < 1536; c += 2048) {
      const short8 v = *(const short8*)(xr + c);
      short8 o;
#pragma unroll
      for (int k = 0; k < 8; k++) {
        float f = bfbits2f((unsigned short)v[k]) * scale * w[c + k];
        const __hip_bfloat16 b = __float2bfloat16(f);
        o[k] = *(const short*)&b;
      }
      *(short8*)(xr + c) = o;
    }
  } else {
    // ---- rope(k_pe)+rmsnorm(kv_c) (body identical to r11 rope_rms_kv;
    //      threads >=96 idle but participate in barriers) ----
    __hip_bfloat16* xr = kv + (size_t)(blockIdx.x - Tc) * 576;
    __shared__ float scale_sh2;
    float ss = 0.f;
    short8 v;
    if (tid < 64) {
      v = *(const short8*)(xr + tid * 8);
#pragma unroll
      for (int k = 0; k < 8; k++) {
        const float f = bfbits2f((unsigned short)v[k]);
        ss += f * f;
      }
    } else if (tid < 96) {
      const int i = tid - 64;
      const float2 cs = tab[i];
      __hip_bfloat16* base = xr + 512;
      const float x1 = __bfloat162float(base[i]);
      const float x2 = __bfloat162float(base[i + 32]);
      base[i] = __float2bfloat16(x1 * cs.x - x2 * cs.y);
      base[i + 32] = __float2bfloat16(x2 * cs.x + x1 * cs.y);
    }
#pragma unroll
    for (int off = 32; off > 0; off >>= 1) ss += __shfl_down(ss, off);
    if (tid == 0) scale_sh2 = rsqrtf(ss / 512.f + 1e-6f);
    __syncthreads();
    if (tid < 64) {
      const float scale = scale_sh2;
      short8 o;
#pragma unroll
      for (int k = 0; k < 8; k++) {
        const __hip_bfloat16 b =
            __float2bfloat16(bfbits2f((unsigned short)v[k]) * scale);
        o[k] = *(const short*)&b;
      }
      *(short8*)(xr + tid * 8) = o;
    }
  }
}

// -------------------- wave-per-token attention (MFMA QK^T, V direct) -------
__global__ __launch_bounds__(256) void attn_wave_token(
    const __hip_bfloat16* __restrict__ q,     // [T][16][192]
    const __hip_bfloat16* __restrict__ kvup,  // [T][16][256] (k_nope|v)
    const __hip_bfloat16* __restrict__ kv,    // [T][576], k_pe at +512
    __hip_bfloat16* __restrict__ ctx) {       // [T][16][128]
  __shared__ __hip_bfloat16 sq[4][16 * 200];
  __shared__ __hip_bfloat16 su[4][16 * 136];  // k_nope only, +8 pad
  __shared__ __hip_bfloat16 skpe[4][64];
  __shared__ float sp[4][16][20];
  const int tid = threadIdx.x;
  const int w = tid >> 6;
  const int lane = tid & 63;
  const int t = blockIdx.x * 4 + w;

  const __hip_bfloat16* qb = q + (size_t)t * 3072;
  const __hip_bfloat16* ub = kvup + (size_t)t * 4096;
#pragma unroll
  for (int i = 0; i < 6; i++) {
    const int u = lane + 64 * i;  // u < 384
    const int row = u / 24;
    *(short8*)(&sq[w][u * 8 + row * 8]) = *(const short8*)(qb + u * 8);
  }
#pragma unroll
  for (int i = 0; i < 4; i++) {
    const int u = lane + 64 * i;  // u < 256
    const int row = u >> 4;
    *(short8*)(&su[w][u * 8 + row * 8]) =
        *(const short8*)(ub + row * 256 + (u & 15) * 8);
  }
  if (lane < 8)
    *(short8*)(&skpe[w][lane * 8]) =
        *(const short8*)(kv + (size_t)t * 576 + 512 + lane * 8);
  __syncthreads();

  const int r15 = lane & 15;
  const int l4 = lane >> 4;

  floatx4 sacc = {0.f, 0.f, 0.f, 0.f};
#pragma unroll
  for (int ks = 0; ks < 4; ks++) {
    const short8 aq = *(const short8*)(&sq[w][r15 * 200 + ks * 32 + l4 * 8]);
    const short8 bk = *(const short8*)(&su[w][r15 * 136 + ks * 32 + l4 * 8]);
    sacc = __builtin_amdgcn_mfma_f32_16x16x32_bf16(aq, bk, sacc, 0, 0, 0);
  }
#pragma unroll
  for (int ks = 4; ks < 6; ks++) {
    const short8 aq = *(const short8*)(&sq[w][r15 * 200 + ks * 32 + l4 * 8]);
    const short8 bk = *(const short8*)(&skpe[w][(ks - 4) * 32 + l4 * 8]);
    sacc = __builtin_amdgcn_mfma_f32_16x16x32_bf16(aq, bk, sacc, 0, 0, 0);
  }

  const int d0 = (lane & 31) * 4;
  float vreg[16][4];
#pragma unroll
  for (int j = 0; j < 16; j++) {
    const short4x v4 = *(const short4x*)(ub + j * 256 + 128 + d0);
#pragma unroll
    for (int k = 0; k < 4; k++) vreg[j][k] = bfbits2f((unsigned short)v4[k]);
  }

  const float scale = 0.07216878364870323f;  // 1/sqrt(192)
  float sv4[4];
#pragma unroll
  for (int r = 0; r < 4; r++) sv4[r] = sacc[r] * scale;
  float mx[4];
#pragma unroll
  for (int r = 0; r < 4; r++) {
    float m = sv4[r];
    m = fmaxf(m, __shfl_xor(m, 1));
    m = fmaxf(m, __shfl_xor(m, 2));
    m = fmaxf(m, __shfl_xor(m, 4));
    m = fmaxf(m, __shfl_xor(m, 8));
    mx[r] = m;
  }
  float e[4];
#pragma unroll
  for (int r = 0; r < 4; r++) {
    e[r] = expf(sv4[r] - mx[r]);
    float s = e[r];
    s += __shfl_xor(s, 1);
    s += __shfl_xor(s, 2);
    s += __shfl_xor(s, 4);
    s += __shfl_xor(s, 8);
    e[r] *= (1.0f / s);
  }
#pragma unroll
  for (int r = 0; r < 4; r++) sp[w][l4 * 4 + r][r15] = e[r];
  __syncthreads();

  const int hb = (lane >> 5) * 8;
  __hip_bfloat16* cb = ctx + (size_t)t * 2048;
#pragma unroll
  for (int g = 0; g < 8; g++) {
    const int hh = hb + g;
    float o[4] = {0.f, 0.f, 0.f, 0.f};
#pragma unroll
    for (int j4 = 0; j4 < 4; j4++) {
      const float4 p4 = *(const float4*)(&sp[w][hh][j4 * 4]);
      const float pj[4] = {p4.x, p4.y, p4.z, p4.w};
#pragma unroll
      for (int jj = 0; jj < 4; jj++) {
        const int j = j4 * 4 + jj;
#pragma unroll
        for (int k = 0; k < 4; k++) o[k] += pj[jj] * vreg[j][k];
      }
    }
    short4x st;
#pragma unroll
    for (int k = 0; k < 4; k++) {
      const __hip_bfloat16 b = __float2bfloat16(o[k]);
      st[k] = *(const short*)&b;
    }
    *(short4x*)(cb + hh * 128 + d0) = st;
  }
}

// ---------------------------------------------------------------------------
extern "C" void kernel_launch(void* const* d_in, const int* in_sizes, int n_in,
                              void* d_out, int out_size, void* d_ws,
                              size_t ws_size, hipStream_t stream) {
  const float* x = (const float*)d_in[0];          // 16384 x 2048
  const float* wq_a = (const float*)d_in[1];       // 2048 x 1536
  const float* q_norm_w = (const float*)d_in[2];   // 1536
  const float* wq_b = (const float*)d_in[3];       // 1536 x 3072
  const float* wkv_a = (const float*)d_in[4];      // 2048 x 576
  const float* wkv_b = (const float*)d_in[5];      // 512 x 4096
  const float* wo = (const float*)d_in[6];         // 2048 x 2048
  const int* start_pos = (const int*)d_in[7];
  float* out = (float*)d_out;

  const int T = 16384;
  __hip_bfloat16* w0 = (__hip_bfloat16*)d_ws;
  __hip_bfloat16* wqkv_aT = w0;                      // 2304 x 2048
  __hip_bfloat16* wq_aT = wqkv_aT;                   // rows 0..1535
  __hip_bfloat16* wkv_aT = wqkv_aT + 1536 * 2048;    // rows 1536..2303 (pad)
  __hip_bfloat16* wq_bT = wqkv_aT + 2304 * 2048;     // 3072 x 1536
  __hip_bfloat16* wkv_bT = wq_bT + 3072 * 1536;      // 4096 x 512
  __hip_bfloat16* woT = wkv_bT + 4096 * 512;         // 2048 x 2048
  float2* rope_tab = (float2*)(woT + 2048 * 2048);   // 4096 x 32 float2 (1MB)
  __hip_bfloat16* chunk0 = (__hip_bfloat16*)(rope_tab + 4096 * 32);
  const size_t w_bytes = (size_t)((char*)chunk0 - (char*)w0);

  const size_t per_tok = 11840 * sizeof(__hip_bfloat16);
  int Tc = T;
  while (Tc > 256 && w_bytes + (size_t)Tc * per_tok > ws_size) Tc >>= 1;

  __hip_bfloat16* xb = chunk0;                       // Tc x 2048
  __hip_bfloat16* q_buf = xb + (size_t)Tc * 2048;    // Tc x 3072
  __hip_bfloat16* kvup = q_buf + (size_t)Tc * 3072;  // Tc x 4096
  __hip_bfloat16* cbuf = kvup + (size_t)Tc * 4096;   // Tc x 2048
  __hip_bfloat16* kv = cbuf + (size_t)Tc * 2048;     // Tc x 576

  dim3 blk(256);
  dim3 blk512(512);

  // prep_all: cast(chunk 0) + 5 weight transposes + rope table, one launch.
  const int ncast = Tc;  // (Tc*2048)/2048 blocks for the cast segment
  prep_all<<<dim3(ncast + 15360 + 512), blk, 0, stream>>>(
      x, wq_a, wkv_a, wq_b, wkv_b, wo, start_pos, xb, wq_aT, wkv_aT, wq_bT,
      wkv_bT, woT, rope_tab, ncast);

  const int nby = Tc / 256;
  for (int t0 = 0; t0 < T; t0 += Tc) {
    if (t0 > 0)
      cast_f32_bf16<<<dim3(Tc), blk, 0, stream>>>(x + (size_t)t0 * 2048, xb);
    // G1+G3 fused: [q_lora | kv] = xb @ [wq_a | wkv_a]^T
    gemm256_8ph<true, false><<<dim3(9 * nby), blk512, 0, stream>>>(
        xb, wqkv_aT, cbuf, 1536, 1536, kv, 576, 576, 2048, 2048, 9,
        nullptr, 0);
    // rmsnorm(cbuf) + rope+rms(kv), one launch
    post_g1g3<<<dim3(2 * Tc), blk, 0, stream>>>(cbuf, q_norm_w, kv, rope_tab,
                                                Tc);
    // G2: q = q_lora @ wq_b^T, rope_q fused into epilogue
    gemm256_8ph<true, true><<<dim3(12 * nby), blk512, 0, stream>>>(
        cbuf, wq_bT, q_buf, 3072, 3072, nullptr, 0, 0, 1536, 1536, 12,
        rope_tab, t0);
    // G4: kvup = kvn @ wkv_b^T (A ld 576, K=512)
    gemm256_8ph<true, false><<<dim3(16 * nby), blk512, 0, stream>>>(
        kv, wkv_bT, kvup, 4096, 4096, nullptr, 0, 0, 512, 576, 16,
        nullptr, 0);
    // attention -> ctx (reuses cbuf)
    attn_wave_token<<<dim3(Tc / 4), blk, 0, stream>>>(q_buf, kvup, kv, cbuf);
    // G5: out = ctx @ wo^T (fp32 out)
    gemm256_8ph<false, false><<<dim3(8 * nby), blk512, 0, stream>>>(
        cbuf, woT, out + (size_t)t0 * 2048, 2048, 2048, nullptr, 0, 0, 2048,
        2048, 8, nullptr, 0);
  }
}